// Round 14
// baseline (655.352 us; speedup 1.0000x reference)
//
#include <hip/hip_runtime.h>
#include <hip/hip_bf16.h>

#define N_NODES 25000
#define N_EDGES 400000
#define NTILES (N_EDGES / 32)   // 12500 exact

typedef __attribute__((ext_vector_type(8))) __bf16 bf16x8;
typedef __attribute__((ext_vector_type(4))) float f32x4;
typedef __attribute__((ext_vector_type(2))) unsigned uint32x2;

// Raw workgroup barrier that does NOT drain vmcnt: waits only LDS ops.
#define BAR() do {                                          \
    asm volatile("s_waitcnt lgkmcnt(0)" ::: "memory");      \
    __builtin_amdgcn_s_barrier();                           \
    asm volatile("" ::: "memory");                          \
} while (0)

static __device__ __forceinline__ unsigned short bfbits(float f) {
    __bf16 h = (__bf16)f;
    return __builtin_bit_cast(unsigned short, h);
}
static __device__ __forceinline__ float bf2f(unsigned short u) {
    return __builtin_bit_cast(float, ((unsigned)u) << 16);
}
static __device__ __forceinline__ float ssp_f(float x) {
    const float t = __builtin_amdgcn_exp2f(x * 1.44269504f);
    return 0.69314718f * (__builtin_amdgcn_logf(1.f + t) - 1.f);
}

// ---------------------------------------------------------------------------
// out[M x 256] = op(A[M x 256] @ B[256 x 256] (+ bias))  (unchanged)
// ---------------------------------------------------------------------------
template<int EPI, int OBF, int ABF>
__global__ __launch_bounds__(256, 2)
void node_gemm(const void* __restrict__ Av, const float* __restrict__ B,
               const float* __restrict__ bias, void* __restrict__ outv, int M)
{
    extern __shared__ char lds[];
    const int tid  = threadIdx.x;
    const int half = blockIdx.x & 1;
    const int jblk = half << 7;
    const int row0 = (blockIdx.x >> 1) << 7;

    {
        const int j   = tid & 127;
        const int k2b = (tid >> 7) << 6;
        for (int i = 0; i < 64; ++i) {
            const int k = (k2b + i) * 2;
            const float b0 = B[k * 256 + jblk + j];
            const float b1 = B[(k + 1) * 256 + jblk + j];
            const unsigned pack = (unsigned)bfbits(b0) | ((unsigned)bfbits(b1) << 16);
            *(unsigned*)(lds + ((j * 512 + k * 2) ^ ((j & 7) << 4))) = pack;
        }
    }
    __syncthreads();

    const int wave = tid >> 6;
    const int l    = tid & 63;
    const int lrow = l & 15;
    const int kg   = (l >> 4) << 3;

    f32x4 acc[8][2];
    const f32x4 z4 = {0.f, 0.f, 0.f, 0.f};
    #pragma unroll
    for (int m = 0; m < 8; ++m) { acc[m][0] = z4; acc[m][1] = z4; }

    #pragma unroll
    for (int ks = 0; ks < 8; ++ks) {
        const int k0 = (ks << 5) + kg;
        bf16x8 bfr[2];
        #pragma unroll
        for (int n = 0; n < 2; ++n) {
            const int jl = (wave << 5) + (n << 4) + lrow;
            bfr[n] = *(const bf16x8*)(lds + ((jl * 512 + k0 * 2) ^ ((jl & 7) << 4)));
        }
        #pragma unroll
        for (int m = 0; m < 8; ++m) {
            const int row = row0 + (m << 4) + lrow;
            bf16x8 af;
            if (row < M) {
                if (ABF) {
                    af = *(const bf16x8*)((const __bf16*)Av + row * 256 + k0);
                } else {
                    const float* ap = (const float*)Av + row * 256 + k0;
                    const f32x4 a0 = *(const f32x4*)(ap);
                    const f32x4 a1 = *(const f32x4*)(ap + 4);
                    #pragma unroll
                    for (int b = 0; b < 4; ++b) { af[b] = (__bf16)a0[b]; af[b + 4] = (__bf16)a1[b]; }
                }
            } else {
                #pragma unroll
                for (int b = 0; b < 8; ++b) af[b] = (__bf16)0.f;
            }
            acc[m][0] = __builtin_amdgcn_mfma_f32_16x16x32_bf16(af, bfr[0], acc[m][0], 0, 0, 0);
            acc[m][1] = __builtin_amdgcn_mfma_f32_16x16x32_bf16(af, bfr[1], acc[m][1], 0, 0, 0);
        }
    }

    #pragma unroll
    for (int m = 0; m < 8; ++m) {
        #pragma unroll
        for (int n = 0; n < 2; ++n) {
            const int j = jblk + (wave << 5) + (n << 4) + lrow;
            float bv = 0.f;
            if (EPI) bv = bias[j];
            #pragma unroll
            for (int r = 0; r < 4; ++r) {
                const int row = row0 + (m << 4) + ((l >> 4) << 2) + r;
                if (row < M) {
                    float v = acc[m][n][r] + bv;
                    if (EPI == 1) v = ssp_f(v);
                    if (OBF) ((unsigned short*)outv)[row * 256 + j] = bfbits(v);
                    else     ((float*)outv)[row * 256 + j] = v;
                }
            }
        }
    }
}

// ---------------------------------------------------------------------------
// Counting sort + meta precompute + fused pos copy (unchanged)
// ---------------------------------------------------------------------------
__global__ void hist_kernel(const int* __restrict__ ei, int* __restrict__ hist)
{
    const int i = blockIdx.x * 256 + threadIdx.x;
    if (i < N_EDGES) atomicAdd(&hist[ei[N_EDGES + i]], 1);
}

__global__ void scan_kernel(int* __restrict__ hist)
{
    __shared__ int part[1024];
    const int t  = threadIdx.x;
    const int CH = (N_NODES + 1023) / 1024;   // 25
    const int lo = t * CH;
    const int hi = (lo + CH < N_NODES) ? lo + CH : N_NODES;
    int s = 0;
    for (int i = lo; i < hi; ++i) s += hist[i];
    part[t] = s;
    __syncthreads();
    for (int off = 1; off < 1024; off <<= 1) {
        const int v = part[t];
        const int u = (t >= off) ? part[t - off] : 0;
        __syncthreads();
        part[t] = v + u;
        __syncthreads();
    }
    int base = (t == 0) ? 0 : part[t - 1];
    for (int i = lo; i < hi; ++i) { const int v = hist[i]; hist[i] = base; base += v; }
}

__global__ void scatter_meta(const int* __restrict__ ei, const float* __restrict__ pos,
                             int* __restrict__ hist, float4* __restrict__ meta,
                             float* __restrict__ out_pos)
{
    const int i = blockIdx.x * 256 + threadIdx.x;
    if (i >= N_EDGES) return;
    if (i < N_NODES * 3) out_pos[i] = pos[i];
    const int r = ei[i];
    const int c = ei[N_EDGES + i];
    const float dx = pos[r * 3 + 0] - pos[c * 3 + 0];
    const float dy = pos[r * 3 + 1] - pos[c * 3 + 1];
    const float dz = pos[r * 3 + 2] - pos[c * 3 + 2];
    const float d  = __fsqrt_rn(dx * dx + dy * dy + dz * dz);
    const float C  = 0.5f * (__cosf(d * 0.31415926535f) + 1.f);
    const int p = atomicAdd(&hist[c], 1);
    float4 m;
    m.x = d; m.y = C;
    m.z = __int_as_float(r); m.w = __int_as_float(c);
    meta[p] = m;
}

// ---------------------------------------------------------------------------
// SPLIT Kernel A: gauss -> GEMM1 -> ssp -> t (bf16 global). 64-edge blocks,
// no loop, 2 barriers, fully parallel (6250 blocks).
// LDS: gs [64 e][64 k] 8K + tb [64 e][256 f] 32K, both XOR-swizzled.
// ---------------------------------------------------------------------------
__global__ __launch_bounds__(256, 2)
void edge_gemm1(const float4* __restrict__ meta,
                const float* __restrict__ w1, const float* __restrict__ b1,
                unsigned short* __restrict__ tg)
{
    __shared__ char gs[8192];
    __shared__ char tb[32768];

    const int tid  = threadIdx.x;
    const int wave = tid >> 6;
    const int l    = tid & 63;
    const int lrow = l & 15;
    const int g    = l >> 4;
    const int kg   = g << 3;
    const int e0   = blockIdx.x << 6;

    const float dlt    = 10.f / 49.f;
    const float coeff2 = (-0.5f / (dlt * dlt)) * 1.44269504f;

    // W1 frags: wave owns filter cols [wave*64, +64)
    bf16x8 w1f[4][2];
    #pragma unroll
    for (int n = 0; n < 4; ++n)
        #pragma unroll
        for (int ks = 0; ks < 2; ++ks) {
            bf16x8 v;
            #pragma unroll
            for (int b = 0; b < 8; ++b) {
                const int k = (ks << 5) + kg + b;
                const int j = (wave << 6) + (n << 4) + lrow;
                v[b] = (k < 50) ? (__bf16)w1[k * 256 + j] : (__bf16)0.f;
            }
            w1f[n][ks] = v;
        }
    float b1v[4];
    #pragma unroll
    for (int n = 0; n < 4; ++n) b1v[n] = b1[(wave << 6) + (n << 4) + lrow];

    // gaussians: 512 slots (64 e x 8 k-slabs), 2 per thread
    #pragma unroll
    for (int s = 0; s < 2; ++s) {
        const int slot = tid + (s << 8);
        const int ge   = slot >> 3;
        const int kb   = (slot & 7) << 3;
        const float gd = meta[e0 + ge].x;
        bf16x8 gv;
        #pragma unroll
        for (int b = 0; b < 8; ++b) {
            const int k = kb + b;
            float gval = 0.f;
            if (k < 50) {
                const float u = gd - (float)k * dlt;
                gval = __builtin_amdgcn_exp2f(coeff2 * u * u);
            }
            gv[b] = (__bf16)gval;
        }
        *(bf16x8*)(gs + ((ge * 128 + (kb << 1)) ^ ((ge & 7) << 4))) = gv;
    }
    __syncthreads();

    // GEMM1: gauss[64][64] @ W1[:, wave cols] -> acc[4][4]; af loaded inline
    f32x4 acc[4][4];
    const f32x4 z4 = {0.f, 0.f, 0.f, 0.f};
    #pragma unroll
    for (int m = 0; m < 4; ++m)
        #pragma unroll
        for (int n = 0; n < 4; ++n) acc[m][n] = z4;
    #pragma unroll
    for (int ks = 0; ks < 2; ++ks) {
        #pragma unroll
        for (int m = 0; m < 4; ++m) {
            const int e = (m << 4) + lrow;
            const bf16x8 af = *(const bf16x8*)(gs + ((e * 128 + (((ks << 5) + kg) << 1)) ^ ((e & 7) << 4)));
            #pragma unroll
            for (int n = 0; n < 4; ++n)
                acc[m][n] = __builtin_amdgcn_mfma_f32_16x16x32_bf16(af, w1f[n][ks], acc[m][n], 0, 0, 0);
        }
    }

    // ssp -> tb (swizzled)
    #pragma unroll
    for (int m = 0; m < 4; ++m)
        #pragma unroll
        for (int n = 0; n < 4; ++n)
            #pragma unroll
            for (int r4 = 0; r4 < 4; ++r4) {
                const int e = (m << 4) + (g << 2) + r4;
                const int k = (wave << 6) + (n << 4) + lrow;
                const float v = ssp_f(acc[m][n][r4] + b1v[n]);
                *(__bf16*)(tb + ((e * 512 + k * 2) ^ ((e & 7) << 4))) = (__bf16)v;
            }
    __syncthreads();

    // coalesced store: 128 B per thread of the linear [64][256] bf16 tile
    char* dst = (char*)tg + (size_t)e0 * 512;
    #pragma unroll
    for (int i = 0; i < 8; ++i) {
        const int lin = tid * 128 + i * 16;
        const int e   = lin >> 9;
        const int kb  = lin & 511;
        const f32x4 v = *(const f32x4*)(tb + ((e * 512 + kb) ^ ((e & 7) << 4)));
        *(f32x4*)(dst + lin) = v;
    }
}

// ---------------------------------------------------------------------------
// SPLIT Kernel B: t -> GEMM2 -> msg -> scatter. Quarter-j blocks (64 j),
// disjoint LDS {w2t 32K | tb 16K | ms 4K | colsm} = 53.4KB -> 3 blocks/CU,
// 2 lgkm-only barriers/tile. t+meta prefetched 1 tile ahead. Quarters of the
// same chunk share bid%8 -> same XCD -> t-tile fetched once per XCD.
// ---------------------------------------------------------------------------
__global__ __launch_bounds__(256, 3)
void edge_gemm2(const float4* __restrict__ meta,
                const unsigned short* __restrict__ tg,
                const float* __restrict__ w2, const float* __restrict__ b2,
                const unsigned short* __restrict__ xb, float* __restrict__ agg)
{
    __shared__ char w2t[32768];   // [64 j][256 k] bf16 swz ^((j&7)<<4)
    __shared__ char tb[16384];    // [32 e][256 k] bf16 swz ^((e&7)<<4)
    __shared__ char ms[4096];     // [64 j][64 B]  bf16 swz ^((j&7)<<4)
    __shared__ int colsm[32];

    const int tid  = threadIdx.x;
    const int wave = tid >> 6;
    const int l    = tid & 63;
    const int lrow = l & 15;
    const int g    = l >> 4;
    const int kg   = g << 3;

    const int chunk = blockIdx.x & 255;
    const int q     = blockIdx.x >> 8;     // j-quarter 0..3 (same XCD per chunk)
    const int jq    = q << 6;

    // stage W2 quarter [64 j][256 k]
    {
        const int j  = tid & 63;
        const int kq = (tid >> 6) << 6;
        for (int i = 0; i < 32; ++i) {
            const int k = kq + i * 2;
            const float v0 = w2[k * 256 + jq + j];
            const float v1 = w2[(k + 1) * 256 + jq + j];
            const unsigned pack = (unsigned)bfbits(v0) | ((unsigned)bfbits(v1) << 16);
            *(unsigned*)(w2t + ((j * 512 + k * 2) ^ ((j & 7) << 4))) = pack;
        }
    }
    const float b2v = b2[jq + (wave << 4) + lrow];
    __syncthreads();   // w2t ready

    const int CH = 49;
    const int t0 = chunk * CH;
    int t1 = t0 + CH; if (t1 > NTILES) t1 = NTILES;

    int   rprev  = -1;
    float rs     = 0.f;
    int   rfirst = 1;
    float* aj    = agg + jq + (tid & 63);

    const f32x4 z4 = {0.f, 0.f, 0.f, 0.f};

    // preload first t-tile (16KB = 64 B/thread) + meta
    f32x4 tpre[4];
    #pragma unroll
    for (int i = 0; i < 4; ++i)
        tpre[i] = *(const f32x4*)((const char*)tg + (size_t)t0 * 16384 + tid * 64 + i * 16);
    float4 mv = meta[(t0 << 5) + (l & 31)];

    for (int t = t0; t < t1; ++t) {
        // write staged t into tb (swizzled); prev GEMM2 reads are >=1 barrier back
        #pragma unroll
        for (int i = 0; i < 4; ++i) {
            const int lin = tid * 64 + i * 16;
            const int e   = lin >> 9;
            const int kb  = lin & 511;
            *(f32x4*)(tb + ((e * 512 + kb) ^ ((e & 7) << 4))) = tpre[i];
        }
        if (tid < 32) colsm[tid] = __float_as_int(mv.w);
        const float Cc = mv.y;
        const int   r  = __float_as_int(mv.z);

        // xv gather: 8 bf16 loads (wave's 16 j), in flight until msg epilogue
        float xvv[2][4];
        #pragma unroll
        for (int m = 0; m < 2; ++m)
            #pragma unroll
            for (int r4 = 0; r4 < 4; ++r4) {
                const int e  = (m << 4) + (g << 2) + r4;
                const int re = __shfl(r, e, 64);
                xvv[m][r4] = bf2f(xb[re * 256 + jq + (wave << 4) + lrow]);
            }

        // prefetch next tile's t + meta (ride across barriers)
        if (t + 1 < t1) {
            mv = meta[((t + 1) << 5) + (l & 31)];
            #pragma unroll
            for (int i = 0; i < 4; ++i)
                tpre[i] = *(const f32x4*)((const char*)tg + (size_t)(t + 1) * 16384 + tid * 64 + i * 16);
        }

        BAR();   // B_a: tb + colsm ready

        // GEMM2: t[32][256] @ W2[:, wave's 16 j] -> acc2[2]
        f32x4 acc2[2] = {z4, z4};
        #pragma unroll
        for (int ks = 0; ks < 8; ++ks) {
            const int k0 = (ks << 5) + kg;
            const int jl = (wave << 4) + lrow;
            const bf16x8 bfr = *(const bf16x8*)(w2t + ((jl * 512 + k0 * 2) ^ ((jl & 7) << 4)));
            #pragma unroll
            for (int m = 0; m < 2; ++m) {
                const int e = (m << 4) + lrow;
                const bf16x8 a = *(const bf16x8*)(tb + ((e * 512 + k0 * 2) ^ ((e & 7) << 4)));
                acc2[m] = __builtin_amdgcn_mfma_f32_16x16x32_bf16(a, bfr, acc2[m], 0, 0, 0);
            }
        }

        // msg: (acc2+b2)*C*x -> ms[j][e]
        #pragma unroll
        for (int m = 0; m < 2; ++m) {
            const int base_e = (m << 4) + (g << 2);
            const int jloc   = (wave << 4) + lrow;
            float vv[4];
            #pragma unroll
            for (int r4 = 0; r4 < 4; ++r4) {
                const int e  = base_e + r4;
                const float Ce = __shfl(Cc, e, 64);
                vv[r4] = (acc2[m][r4] + b2v) * Ce * xvv[m][r4];
            }
            uint32x2 pk;
            pk[0] = (unsigned)bfbits(vv[0]) | ((unsigned)bfbits(vv[1]) << 16);
            pk[1] = (unsigned)bfbits(vv[2]) | ((unsigned)bfbits(vv[3]) << 16);
            *(uint32x2*)(ms + ((jloc * 64 + (base_e << 1)) ^ ((jloc & 7) << 4))) = pk;
        }

        BAR();   // B_b: ms ready

        // reader: 64 threads (wave 0), one j each; run-carry reduce
        if (tid < 64) {
            const int j = tid;
            const bf16x8 q0 = *(const bf16x8*)(ms + ((j * 64 +  0) ^ ((j & 7) << 4)));
            const bf16x8 q1 = *(const bf16x8*)(ms + ((j * 64 + 16) ^ ((j & 7) << 4)));
            const bf16x8 q2 = *(const bf16x8*)(ms + ((j * 64 + 32) ^ ((j & 7) << 4)));
            const bf16x8 q3 = *(const bf16x8*)(ms + ((j * 64 + 48) ^ ((j & 7) << 4)));
            #pragma unroll
            for (int e = 0; e < 32; ++e) {
                const float v = (float)(e < 8 ? q0[e] : e < 16 ? q1[e - 8] :
                                        e < 24 ? q2[e - 16] : q3[e - 24]);
                const int ce = colsm[e];
                if (ce != rprev) {
                    if (rprev >= 0) {
                        if (rfirst) { atomicAdd(aj + rprev * 256, rs); rfirst = 0; }
                        else        { aj[rprev * 256] = rs; }
                    }
                    rs = 0.f; rprev = ce;
                }
                rs += v;
            }
        }
    }
    if (tid < 64 && rprev >= 0) atomicAdd(aj + rprev * 256, rs);
}

// ---------------------------------------------------------------------------
// FALLBACK: R13 fused edge kernel (used when ws_size can't hold the t buffer)
// ---------------------------------------------------------------------------
__global__ __launch_bounds__(256, 2)
void edge_kernel(const float4* __restrict__ meta,
                 const float* __restrict__ w1, const float* __restrict__ b1,
                 const float* __restrict__ w2, const float* __restrict__ b2,
                 const unsigned short* __restrict__ xb, float* __restrict__ agg)
{
    extern __shared__ char lds[];
    char* w2t = lds;
    char* rb  = lds + 65536;
    int* colsm = (int*)(rb + 8192);

    const int tid   = threadIdx.x;
    const int wave  = tid >> 6;
    const int l     = tid & 63;
    const int lrow  = l & 15;
    const int g     = l >> 4;
    const int kg    = g << 3;
    const int half  = blockIdx.x & 1;
    const int jblk  = half << 7;
    const int group = blockIdx.x >> 1;

    {
        const int j   = tid & 127;
        const int k2b = (tid >> 7) << 6;
        for (int i = 0; i < 64; ++i) {
            const int k = (k2b + i) * 2;
            const float v0 = w2[k * 256 + jblk + j];
            const float v1 = w2[(k + 1) * 256 + jblk + j];
            const unsigned pack = (unsigned)bfbits(v0) | ((unsigned)bfbits(v1) << 16);
            *(unsigned*)(w2t + ((j * 512 + k * 2) ^ ((j & 7) << 4))) = pack;
        }
    }

    const float dlt    = 10.f / 49.f;
    const float coeff2 = (-0.5f / (dlt * dlt)) * 1.44269504f;
    bf16x8 w1f[4][2];
    #pragma unroll
    for (int n = 0; n < 4; ++n)
        #pragma unroll
        for (int ks = 0; ks < 2; ++ks) {
            bf16x8 v;
            #pragma unroll
            for (int b = 0; b < 8; ++b) {
                const int k = (ks << 5) + kg + b;
                const int j = (wave << 6) + (n << 4) + lrow;
                v[b] = (k < 50) ? (__bf16)w1[k * 256 + j] : (__bf16)0.f;
            }
            w1f[n][ks] = v;
        }
    float b1v[4], b2v[2];
    #pragma unroll
    for (int n = 0; n < 4; ++n) b1v[n] = b1[(wave << 6) + (n << 4) + lrow];
    #pragma unroll
    for (int n = 0; n < 2; ++n) b2v[n] = b2[jblk + (wave << 5) + (n << 4) + lrow];

    BAR();

    const f32x4 z4 = {0.f, 0.f, 0.f, 0.f};
    const int CH = (NTILES + 255) / 256;
    const int t0 = group * CH;
    int t1 = t0 + CH; if (t1 > NTILES) t1 = NTILES;

    const int ge  = tid >> 3;
    const int gkb = (tid & 7) << 3;

    int   rprev  = -1;
    float rs     = 0.f;
    int   rfirst = 1;
    float* aj    = agg + jblk + (tid & 127);

    float4 mv = meta[(t0 << 5) + (l & 31)];

    for (int t = t0; t < t1; ++t) {
        const float d  = mv.x;
        const float Cc = mv.y;
        const int   r  = __float_as_int(mv.z);
        const int   c  = __float_as_int(mv.w);
        if (t + 1 < t1) mv = meta[((t + 1) << 5) + (l & 31)];

        float xv[2][2][4];
        #pragma unroll
        for (int m = 0; m < 2; ++m)
            #pragma unroll
            for (int r4 = 0; r4 < 4; ++r4) {
                const int e  = (m << 4) + (g << 2) + r4;
                const int re = __shfl(r, e, 64);
                #pragma unroll
                for (int n = 0; n < 2; ++n) {
                    const int jloc = (wave << 5) + (n << 4) + lrow;
                    xv[m][n][r4] = bf2f(xb[re * 256 + jblk + jloc]);
                }
            }

        const float gd = __shfl(d, ge, 64);
        bf16x8 gv;
        #pragma unroll
        for (int b = 0; b < 8; ++b) {
            const int k = gkb + b;
            float gval = 0.f;
            if (k < 50) {
                const float u = gd - (float)k * dlt;
                gval = __builtin_amdgcn_exp2f(coeff2 * u * u);
            }
            gv[b] = (__bf16)gval;
        }

        BAR();
        *(bf16x8*)(rb + ((ge * 128 + (gkb << 1)) ^ ((ge & 7) << 4))) = gv;
        BAR();

        bf16x8 af[2][2];
        #pragma unroll
        for (int m = 0; m < 2; ++m) {
            const int e = (m << 4) + lrow;
            #pragma unroll
            for (int ks = 0; ks < 2; ++ks)
                af[m][ks] = *(const bf16x8*)(rb + ((e * 128 + ((ks << 5) + kg) * 2) ^ ((e & 7) << 4)));
        }
        f32x4 acc1[2][4];
        #pragma unroll
        for (int m = 0; m < 2; ++m)
            #pragma unroll
            for (int n = 0; n < 4; ++n) acc1[m][n] = z4;
        #pragma unroll
        for (int ks = 0; ks < 2; ++ks)
            #pragma unroll
            for (int m = 0; m < 2; ++m)
                #pragma unroll
                for (int n = 0; n < 4; ++n)
                    acc1[m][n] = __builtin_amdgcn_mfma_f32_16x16x32_bf16(af[m][ks], w1f[n][ks], acc1[m][n], 0, 0, 0);
        BAR();

        #pragma unroll
        for (int m = 0; m < 2; ++m)
            #pragma unroll
            for (int n = 0; n < 4; ++n)
                #pragma unroll
                for (int r4 = 0; r4 < 4; ++r4) {
                    const int e = (m << 4) + (g << 2) + r4;
                    const int k = (wave << 6) + (n << 4) + lrow;
                    const float v = ssp_f(acc1[m][n][r4] + b1v[n]);
                    *(__bf16*)(rb + ((e * 512 + k * 2) ^ ((e & 7) << 4))) = (__bf16)v;
                }
        BAR();

        f32x4 acc2[2][2];
        #pragma unroll
        for (int m = 0; m < 2; ++m) { acc2[m][0] = z4; acc2[m][1] = z4; }
        #pragma unroll
        for (int ks = 0; ks < 8; ++ks) {
            const int k0 = (ks << 5) + kg;
            bf16x8 bfr[2];
            #pragma unroll
            for (int n = 0; n < 2; ++n) {
                const int jl = (wave << 5) + (n << 4) + lrow;
                bfr[n] = *(const bf16x8*)(w2t + ((jl * 512 + k0 * 2) ^ ((jl & 7) << 4)));
            }
            #pragma unroll
            for (int m = 0; m < 2; ++m) {
                const int e = (m << 4) + lrow;
                const bf16x8 a = *(const bf16x8*)(rb + ((e * 512 + k0 * 2) ^ ((e & 7) << 4)));
                #pragma unroll
                for (int n = 0; n < 2; ++n)
                    acc2[m][n] = __builtin_amdgcn_mfma_f32_16x16x32_bf16(a, bfr[n], acc2[m][n], 0, 0, 0);
            }
        }
        BAR();

        #pragma unroll
        for (int m = 0; m < 2; ++m) {
            const int base_e = (m << 4) + (g << 2);
            #pragma unroll
            for (int n = 0; n < 2; ++n) {
                const int jloc = (wave << 5) + (n << 4) + lrow;
                float vv[4];
                #pragma unroll
                for (int r4 = 0; r4 < 4; ++r4) {
                    const int e  = base_e + r4;
                    const float Ce = __shfl(Cc, e, 64);
                    vv[r4] = (acc2[m][n][r4] + b2v[n]) * Ce * xv[m][n][r4];
                }
                uint32x2 pk;
                pk[0] = (unsigned)bfbits(vv[0]) | ((unsigned)bfbits(vv[1]) << 16);
                pk[1] = (unsigned)bfbits(vv[2]) | ((unsigned)bfbits(vv[3]) << 16);
                *(uint32x2*)(rb + ((jloc * 64 + (base_e << 1)) ^ ((jloc & 7) << 4))) = pk;
            }
        }
        if (tid < 32) colsm[tid] = c;
        BAR();

        if (tid < 128) {
            const int j = tid;
            const bf16x8 q0 = *(const bf16x8*)(rb + ((j * 64 +  0) ^ ((j & 7) << 4)));
            const bf16x8 q1 = *(const bf16x8*)(rb + ((j * 64 + 16) ^ ((j & 7) << 4)));
            const bf16x8 q2 = *(const bf16x8*)(rb + ((j * 64 + 32) ^ ((j & 7) << 4)));
            const bf16x8 q3 = *(const bf16x8*)(rb + ((j * 64 + 48) ^ ((j & 7) << 4)));
            #pragma unroll
            for (int e = 0; e < 32; ++e) {
                const float v = (float)(e < 8 ? q0[e] : e < 16 ? q1[e - 8] :
                                        e < 24 ? q2[e - 16] : q3[e - 24]);
                const int ce = colsm[e];
                if (ce != rprev) {
                    if (rprev >= 0) {
                        if (rfirst) { atomicAdd(aj + rprev * 256, rs); rfirst = 0; }
                        else        { aj[rprev * 256] = rs; }
                    }
                    rs = 0.f; rprev = ce;
                }
                rs += v;
            }
        }
    }
    if (tid < 128 && rprev >= 0) atomicAdd(aj + rprev * 256, rs);
}

extern "C" void kernel_launch(void* const* d_in, const int* in_sizes, int n_in,
                              void* d_out, int out_size, void* d_ws, size_t ws_size,
                              hipStream_t stream)
{
    const float* h      = (const float*)d_in[0];
    const float* pos    = (const float*)d_in[1];
    const float* lin1_w = (const float*)d_in[2];
    const float* lin2_w = (const float*)d_in[3];
    const float* lin2_b = (const float*)d_in[4];
    const float* mlp_w1 = (const float*)d_in[5];
    const float* mlp_b1 = (const float*)d_in[6];
    const float* mlp_w2 = (const float*)d_in[7];
    const float* mlp_b2 = (const float*)d_in[8];
    const float* lin_w  = (const float*)d_in[9];
    const float* lin_b  = (const float*)d_in[10];
    const int*   ei     = (const int*)d_in[11];
    float* out = (float*)d_out;

    // ws layout: xb bf16 12.8M | agg 25.6M | meta 6.4M | hist 0.1M | t 204.8M
    unsigned short* xb  = (unsigned short*)d_ws;
    float*  agg  = (float*)((char*)d_ws + 12800000);
    float4* meta = (float4*)((char*)d_ws + 38400000);
    int*    hist = (int*)((char*)d_ws + 44800000);
    unsigned short* tg = (unsigned short*)((char*)d_ws + 44900000);
    const bool use_split = (ws_size >= 249700000ULL);

    (void)hipFuncSetAttribute((const void*)edge_kernel,
                              hipFuncAttributeMaxDynamicSharedMemorySize, 81920);
    (void)hipFuncSetAttribute((const void*)node_gemm<0, 1, 0>,
                              hipFuncAttributeMaxDynamicSharedMemorySize, 65536);
    (void)hipFuncSetAttribute((const void*)node_gemm<1, 1, 0>,
                              hipFuncAttributeMaxDynamicSharedMemorySize, 65536);
    (void)hipFuncSetAttribute((const void*)node_gemm<2, 0, 1>,
                              hipFuncAttributeMaxDynamicSharedMemorySize, 65536);

    (void)hipMemsetAsync(agg, 0, (size_t)N_NODES * 256 * sizeof(float), stream);
    (void)hipMemsetAsync(hist, 0, (size_t)N_NODES * sizeof(int), stream);

    const dim3 blk(256);
    const int mt = (N_NODES + 127) / 128;
    const int eb = (N_EDGES + 255) / 256;

    // x = bf16(h @ lin1_w)
    node_gemm<0, 1, 0><<<dim3(mt * 2), blk, 65536, stream>>>(h, lin1_w, nullptr, xb, N_NODES);

    // counting sort by col + per-edge meta + fused pos copy
    hist_kernel<<<dim3(eb), blk, 0, stream>>>(ei, hist);
    scan_kernel<<<dim3(1), dim3(1024), 0, stream>>>(hist);
    scatter_meta<<<dim3(eb), blk, 0, stream>>>(ei, pos, hist, meta, out + N_NODES * 256);

    if (use_split) {
        // A: gauss+GEMM1+ssp -> t ; B: t@W2 -> msg -> scatter
        edge_gemm1<<<dim3(N_EDGES / 64), blk, 0, stream>>>(meta, mlp_w1, mlp_b1, tg);
        edge_gemm2<<<dim3(1024), blk, 0, stream>>>(meta, tg, mlp_w2, mlp_b2, xb, agg);
    } else {
        edge_kernel<<<dim3(512), blk, 81920, stream>>>(meta, mlp_w1, mlp_b1,
                                                       mlp_w2, mlp_b2, xb, agg);
    }

    // x2 = bf16(ssp(agg @ lin2_w + lin2_b))
    node_gemm<1, 1, 0><<<dim3(mt * 2), blk, 65536, stream>>>(agg, lin2_w, lin2_b, xb, N_NODES);
    // h_update = x2 @ lin_w + lin_b
    node_gemm<2, 0, 1><<<dim3(mt * 2), blk, 65536, stream>>>(xb, lin_w, lin_b, out, N_NODES);
}

// Round 15
// 484.945 us; speedup vs baseline: 1.3514x; 1.3514x over previous
//
#include <hip/hip_runtime.h>
#include <hip/hip_bf16.h>

#define N_NODES 25000
#define N_EDGES 400000
#define NTILES (N_EDGES / 32)   // 12500 exact

typedef __attribute__((ext_vector_type(8))) __bf16 bf16x8;
typedef __attribute__((ext_vector_type(4))) float f32x4;
typedef __attribute__((ext_vector_type(2))) unsigned uint32x2;

// Raw workgroup barrier that does NOT drain vmcnt: waits only LDS ops.
#define BAR() do {                                          \
    asm volatile("s_waitcnt lgkmcnt(0)" ::: "memory");      \
    __builtin_amdgcn_s_barrier();                           \
    asm volatile("" ::: "memory");                          \
} while (0)

static __device__ __forceinline__ unsigned short bfbits(float f) {
    __bf16 h = (__bf16)f;
    return __builtin_bit_cast(unsigned short, h);
}
static __device__ __forceinline__ float bf2f(unsigned short u) {
    return __builtin_bit_cast(float, ((unsigned)u) << 16);
}
static __device__ __forceinline__ float ssp_f(float x) {
    const float t = __builtin_amdgcn_exp2f(x * 1.44269504f);
    return 0.69314718f * (__builtin_amdgcn_logf(1.f + t) - 1.f);
}

// ---------------------------------------------------------------------------
// out[M x 256] = op(A[M x 256] @ B[256 x 256] (+ bias))  (unchanged)
// ---------------------------------------------------------------------------
template<int EPI, int OBF, int ABF>
__global__ __launch_bounds__(256, 2)
void node_gemm(const void* __restrict__ Av, const float* __restrict__ B,
               const float* __restrict__ bias, void* __restrict__ outv, int M)
{
    extern __shared__ char lds[];
    const int tid  = threadIdx.x;
    const int half = blockIdx.x & 1;
    const int jblk = half << 7;
    const int row0 = (blockIdx.x >> 1) << 7;

    {
        const int j   = tid & 127;
        const int k2b = (tid >> 7) << 6;
        for (int i = 0; i < 64; ++i) {
            const int k = (k2b + i) * 2;
            const float b0 = B[k * 256 + jblk + j];
            const float b1 = B[(k + 1) * 256 + jblk + j];
            const unsigned pack = (unsigned)bfbits(b0) | ((unsigned)bfbits(b1) << 16);
            *(unsigned*)(lds + ((j * 512 + k * 2) ^ ((j & 7) << 4))) = pack;
        }
    }
    __syncthreads();

    const int wave = tid >> 6;
    const int l    = tid & 63;
    const int lrow = l & 15;
    const int kg   = (l >> 4) << 3;

    f32x4 acc[8][2];
    const f32x4 z4 = {0.f, 0.f, 0.f, 0.f};
    #pragma unroll
    for (int m = 0; m < 8; ++m) { acc[m][0] = z4; acc[m][1] = z4; }

    #pragma unroll
    for (int ks = 0; ks < 8; ++ks) {
        const int k0 = (ks << 5) + kg;
        bf16x8 bfr[2];
        #pragma unroll
        for (int n = 0; n < 2; ++n) {
            const int jl = (wave << 5) + (n << 4) + lrow;
            bfr[n] = *(const bf16x8*)(lds + ((jl * 512 + k0 * 2) ^ ((jl & 7) << 4)));
        }
        #pragma unroll
        for (int m = 0; m < 8; ++m) {
            const int row = row0 + (m << 4) + lrow;
            bf16x8 af;
            if (row < M) {
                if (ABF) {
                    af = *(const bf16x8*)((const __bf16*)Av + row * 256 + k0);
                } else {
                    const float* ap = (const float*)Av + row * 256 + k0;
                    const f32x4 a0 = *(const f32x4*)(ap);
                    const f32x4 a1 = *(const f32x4*)(ap + 4);
                    #pragma unroll
                    for (int b = 0; b < 4; ++b) { af[b] = (__bf16)a0[b]; af[b + 4] = (__bf16)a1[b]; }
                }
            } else {
                #pragma unroll
                for (int b = 0; b < 8; ++b) af[b] = (__bf16)0.f;
            }
            acc[m][0] = __builtin_amdgcn_mfma_f32_16x16x32_bf16(af, bfr[0], acc[m][0], 0, 0, 0);
            acc[m][1] = __builtin_amdgcn_mfma_f32_16x16x32_bf16(af, bfr[1], acc[m][1], 0, 0, 0);
        }
    }

    #pragma unroll
    for (int m = 0; m < 8; ++m) {
        #pragma unroll
        for (int n = 0; n < 2; ++n) {
            const int j = jblk + (wave << 5) + (n << 4) + lrow;
            float bv = 0.f;
            if (EPI) bv = bias[j];
            #pragma unroll
            for (int r = 0; r < 4; ++r) {
                const int row = row0 + (m << 4) + ((l >> 4) << 2) + r;
                if (row < M) {
                    float v = acc[m][n][r] + bv;
                    if (EPI == 1) v = ssp_f(v);
                    if (OBF) ((unsigned short*)outv)[row * 256 + j] = bfbits(v);
                    else     ((float*)outv)[row * 256 + j] = v;
                }
            }
        }
    }
}

// ---------------------------------------------------------------------------
// Counting sort + meta precompute + fused pos copy (unchanged)
// ---------------------------------------------------------------------------
__global__ void hist_kernel(const int* __restrict__ ei, int* __restrict__ hist)
{
    const int i = blockIdx.x * 256 + threadIdx.x;
    if (i < N_EDGES) atomicAdd(&hist[ei[N_EDGES + i]], 1);
}

__global__ void scan_kernel(int* __restrict__ hist)
{
    __shared__ int part[1024];
    const int t  = threadIdx.x;
    const int CH = (N_NODES + 1023) / 1024;   // 25
    const int lo = t * CH;
    const int hi = (lo + CH < N_NODES) ? lo + CH : N_NODES;
    int s = 0;
    for (int i = lo; i < hi; ++i) s += hist[i];
    part[t] = s;
    __syncthreads();
    for (int off = 1; off < 1024; off <<= 1) {
        const int v = part[t];
        const int u = (t >= off) ? part[t - off] : 0;
        __syncthreads();
        part[t] = v + u;
        __syncthreads();
    }
    int base = (t == 0) ? 0 : part[t - 1];
    for (int i = lo; i < hi; ++i) { const int v = hist[i]; hist[i] = base; base += v; }
}

__global__ void scatter_meta(const int* __restrict__ ei, const float* __restrict__ pos,
                             int* __restrict__ hist, float4* __restrict__ meta,
                             float* __restrict__ out_pos)
{
    const int i = blockIdx.x * 256 + threadIdx.x;
    if (i >= N_EDGES) return;
    if (i < N_NODES * 3) out_pos[i] = pos[i];
    const int r = ei[i];
    const int c = ei[N_EDGES + i];
    const float dx = pos[r * 3 + 0] - pos[c * 3 + 0];
    const float dy = pos[r * 3 + 1] - pos[c * 3 + 1];
    const float dz = pos[r * 3 + 2] - pos[c * 3 + 2];
    const float d  = __fsqrt_rn(dx * dx + dy * dy + dz * dz);
    const float C  = 0.5f * (__cosf(d * 0.31415926535f) + 1.f);
    const int p = atomicAdd(&hist[c], 1);
    float4 m;
    m.x = d; m.y = C;
    m.z = __int_as_float(r); m.w = __int_as_float(c);
    meta[p] = m;
}

// ---------------------------------------------------------------------------
// Fused edge kernel over SORTED edges (R13 base, measured 269us).
// R15 delta: gaussian A-fragments computed IN REGISTERS (no gs region, no
// producer/consumer LDS roundtrip) -> barriers 6 -> 4 per tile, and the
// register-only af+GEMM1 block sits BEFORE the loop-top barrier so it
// overlaps the previous tile's reader phase.
// Barriers: B_top (reader done -> tb writable), B_a (tb ready),
//           B_b (tb reads done -> ms writable), B_c (ms+colsm ready).
// ---------------------------------------------------------------------------
__global__ __launch_bounds__(256, 2)
void edge_kernel(const float4* __restrict__ meta,
                 const float* __restrict__ w1, const float* __restrict__ b1,
                 const float* __restrict__ w2, const float* __restrict__ b2,
                 const unsigned short* __restrict__ xb, float* __restrict__ agg)
{
    extern __shared__ char lds[];
    char* w2t = lds;
    char* rb  = lds + 65536;          // union: tb[0:16K]; ms[0:8K]; colsm at +8K
    int* colsm = (int*)(rb + 8192);

    const int tid   = threadIdx.x;
    const int wave  = tid >> 6;
    const int l     = tid & 63;
    const int lrow  = l & 15;
    const int g     = l >> 4;
    const int kg    = g << 3;
    const int half  = blockIdx.x & 1;
    const int jblk  = half << 7;
    const int group = blockIdx.x >> 1;

    // stage W2^T half
    {
        const int j   = tid & 127;
        const int k2b = (tid >> 7) << 6;
        for (int i = 0; i < 64; ++i) {
            const int k = (k2b + i) * 2;
            const float v0 = w2[k * 256 + jblk + j];
            const float v1 = w2[(k + 1) * 256 + jblk + j];
            const unsigned pack = (unsigned)bfbits(v0) | ((unsigned)bfbits(v1) << 16);
            *(unsigned*)(w2t + ((j * 512 + k * 2) ^ ((j & 7) << 4))) = pack;
        }
    }

    // W1 B-fragments in registers (wave owns 64 filter cols)
    const float dlt    = 10.f / 49.f;
    const float coeff2 = (-0.5f / (dlt * dlt)) * 1.44269504f;   // log2e folded
    bf16x8 w1f[4][2];
    #pragma unroll
    for (int n = 0; n < 4; ++n)
        #pragma unroll
        for (int ks = 0; ks < 2; ++ks) {
            bf16x8 v;
            #pragma unroll
            for (int b = 0; b < 8; ++b) {
                const int k = (ks << 5) + kg + b;
                const int j = (wave << 6) + (n << 4) + lrow;
                v[b] = (k < 50) ? (__bf16)w1[k * 256 + j] : (__bf16)0.f;
            }
            w1f[n][ks] = v;
        }
    float b1v[4], b2v[2];
    #pragma unroll
    for (int n = 0; n < 4; ++n) b1v[n] = b1[(wave << 6) + (n << 4) + lrow];
    #pragma unroll
    for (int n = 0; n < 2; ++n) b2v[n] = b2[jblk + (wave << 5) + (n << 4) + lrow];

    BAR();   // w2t ready

    const f32x4 z4 = {0.f, 0.f, 0.f, 0.f};
    const int CH = (NTILES + 255) / 256;    // 49 tiles per group, contiguous
    const int t0 = group * CH;
    int t1 = t0 + CH; if (t1 > NTILES) t1 = NTILES;

    // reader run-carry state (used by tid < 128 only)
    int   rprev  = -1;
    float rs     = 0.f;
    int   rfirst = 1;
    float* aj    = agg + jblk + (tid & 127);

    // meta prefetch
    float4 mv = meta[(t0 << 5) + (l & 31)];

    for (int t = t0; t < t1; ++t) {
        const float d  = mv.x;
        const float Cc = mv.y;
        const int   r  = __float_as_int(mv.z);
        const int   c  = __float_as_int(mv.w);
        if (t + 1 < t1) mv = meta[((t + 1) << 5) + (l & 31)];

        // hoisted bf16 x-gather (in flight until msg epilogue)
        float xv[2][2][4];
        #pragma unroll
        for (int m = 0; m < 2; ++m)
            #pragma unroll
            for (int r4 = 0; r4 < 4; ++r4) {
                const int e  = (m << 4) + (g << 2) + r4;
                const int re = __shfl(r, e, 64);
                #pragma unroll
                for (int n = 0; n < 2; ++n) {
                    const int jloc = (wave << 5) + (n << 4) + lrow;
                    xv[m][n][r4] = bf2f(xb[re * 256 + jblk + jloc]);
                }
            }

        // ---- in-register gaussian A-fragments (no LDS, no barriers) ----
        const float de0 = __shfl(d, lrow, 64);        // edge e = lrow
        const float de1 = __shfl(d, 16 + lrow, 64);   // edge e = 16 + lrow
        bf16x8 af[2][2];
        #pragma unroll
        for (int m = 0; m < 2; ++m) {
            const float de = m ? de1 : de0;
            #pragma unroll
            for (int ks = 0; ks < 2; ++ks) {
                bf16x8 v;
                #pragma unroll
                for (int b = 0; b < 8; ++b) {
                    const int k = (ks << 5) + kg + b;
                    float gval = 0.f;
                    if (k < 50) {
                        const float u = de - (float)k * dlt;
                        gval = __builtin_amdgcn_exp2f(coeff2 * u * u);
                    }
                    v[b] = (__bf16)gval;
                }
                af[m][ks] = v;
            }
        }

        // ---- GEMM1 (register-only; overlaps prev tile's reader) ----
        f32x4 acc1[2][4];
        #pragma unroll
        for (int m = 0; m < 2; ++m)
            #pragma unroll
            for (int n = 0; n < 4; ++n) acc1[m][n] = z4;
        #pragma unroll
        for (int ks = 0; ks < 2; ++ks)
            #pragma unroll
            for (int m = 0; m < 2; ++m)
                #pragma unroll
                for (int n = 0; n < 4; ++n)
                    acc1[m][n] = __builtin_amdgcn_mfma_f32_16x16x32_bf16(af[m][ks], w1f[n][ks], acc1[m][n], 0, 0, 0);

        BAR();   // B_top: prev reader done with ms/colsm -> tb writable

        // ---- ssp epilogue -> tb (swizzled) ----
        #pragma unroll
        for (int m = 0; m < 2; ++m)
            #pragma unroll
            for (int n = 0; n < 4; ++n)
                #pragma unroll
                for (int r4 = 0; r4 < 4; ++r4) {
                    const int e = (m << 4) + (g << 2) + r4;
                    const int k = (wave << 6) + (n << 4) + lrow;
                    const float v = ssp_f(acc1[m][n][r4] + b1v[n]);
                    *(__bf16*)(rb + ((e * 512 + k * 2) ^ ((e & 7) << 4))) = (__bf16)v;
                }
        BAR();   // B_a: tb ready

        // ---- GEMM2: t[32][256] @ W2[:, jblk:+128] -> acc2 ----
        f32x4 acc2[2][2];
        #pragma unroll
        for (int m = 0; m < 2; ++m) { acc2[m][0] = z4; acc2[m][1] = z4; }
        #pragma unroll
        for (int ks = 0; ks < 8; ++ks) {
            const int k0 = (ks << 5) + kg;
            bf16x8 bfr[2];
            #pragma unroll
            for (int n = 0; n < 2; ++n) {
                const int jl = (wave << 5) + (n << 4) + lrow;
                bfr[n] = *(const bf16x8*)(w2t + ((jl * 512 + k0 * 2) ^ ((jl & 7) << 4)));
            }
            #pragma unroll
            for (int m = 0; m < 2; ++m) {
                const int e = (m << 4) + lrow;
                const bf16x8 a = *(const bf16x8*)(rb + ((e * 512 + k0 * 2) ^ ((e & 7) << 4)));
                #pragma unroll
                for (int n = 0; n < 2; ++n)
                    acc2[m][n] = __builtin_amdgcn_mfma_f32_16x16x32_bf16(a, bfr[n], acc2[m][n], 0, 0, 0);
            }
        }
        BAR();   // B_b: tb reads done -> ms writable

        // ---- msg epilogue: (acc2+b2)*C * xv -> ms[j][e] bf16 (swizzled) ----
        #pragma unroll
        for (int m = 0; m < 2; ++m) {
            const int base_e = (m << 4) + (g << 2);
            #pragma unroll
            for (int n = 0; n < 2; ++n) {
                const int jloc = (wave << 5) + (n << 4) + lrow;
                float vv[4];
                #pragma unroll
                for (int r4 = 0; r4 < 4; ++r4) {
                    const int e  = base_e + r4;
                    const float Ce = __shfl(Cc, e, 64);
                    vv[r4] = (acc2[m][n][r4] + b2v[n]) * Ce * xv[m][n][r4];
                }
                uint32x2 pk;
                pk[0] = (unsigned)bfbits(vv[0]) | ((unsigned)bfbits(vv[1]) << 16);
                pk[1] = (unsigned)bfbits(vv[2]) | ((unsigned)bfbits(vv[3]) << 16);
                *(uint32x2*)(rb + ((jloc * 64 + (base_e << 1)) ^ ((jloc & 7) << 4))) = pk;
            }
        }
        if (tid < 32) colsm[tid] = c;
        BAR();   // B_c: ms + colsm ready

        // ---- reader: 128 threads, one j each, 32 edges; run-carry reduce ----
        if (tid < 128) {
            const int j = tid;
            const bf16x8 q0 = *(const bf16x8*)(rb + ((j * 64 +  0) ^ ((j & 7) << 4)));
            const bf16x8 q1 = *(const bf16x8*)(rb + ((j * 64 + 16) ^ ((j & 7) << 4)));
            const bf16x8 q2 = *(const bf16x8*)(rb + ((j * 64 + 32) ^ ((j & 7) << 4)));
            const bf16x8 q3 = *(const bf16x8*)(rb + ((j * 64 + 48) ^ ((j & 7) << 4)));
            #pragma unroll
            for (int e = 0; e < 32; ++e) {
                const float v = (float)(e < 8 ? q0[e] : e < 16 ? q1[e - 8] :
                                        e < 24 ? q2[e - 16] : q3[e - 24]);
                const int ce = colsm[e];
                if (ce != rprev) {                    // wave-uniform branch
                    if (rprev >= 0) {
                        if (rfirst) { atomicAdd(aj + rprev * 256, rs); rfirst = 0; }
                        else        { aj[rprev * 256] = rs; }
                    }
                    rs = 0.f; rprev = ce;
                }
                rs += v;
            }
        }
    }
    // final flush: run may continue into the next chunk -> atomic
    if (tid < 128 && rprev >= 0) atomicAdd(aj + rprev * 256, rs);
}

extern "C" void kernel_launch(void* const* d_in, const int* in_sizes, int n_in,
                              void* d_out, int out_size, void* d_ws, size_t ws_size,
                              hipStream_t stream)
{
    const float* h      = (const float*)d_in[0];
    const float* pos    = (const float*)d_in[1];
    const float* lin1_w = (const float*)d_in[2];
    const float* lin2_w = (const float*)d_in[3];
    const float* lin2_b = (const float*)d_in[4];
    const float* mlp_w1 = (const float*)d_in[5];
    const float* mlp_b1 = (const float*)d_in[6];
    const float* mlp_w2 = (const float*)d_in[7];
    const float* mlp_b2 = (const float*)d_in[8];
    const float* lin_w  = (const float*)d_in[9];
    const float* lin_b  = (const float*)d_in[10];
    const int*   ei     = (const int*)d_in[11];
    float* out = (float*)d_out;

    // ws layout: xb bf16 12.8M | agg 25.6M | meta 6.4M | hist 0.1M
    unsigned short* xb  = (unsigned short*)d_ws;
    float*  agg  = (float*)((char*)d_ws + 12800000);
    float4* meta = (float4*)((char*)d_ws + 38400000);
    int*    hist = (int*)((char*)d_ws + 44800000);

    (void)hipFuncSetAttribute((const void*)edge_kernel,
                              hipFuncAttributeMaxDynamicSharedMemorySize, 81920);
    (void)hipFuncSetAttribute((const void*)node_gemm<0, 1, 0>,
                              hipFuncAttributeMaxDynamicSharedMemorySize, 65536);
    (void)hipFuncSetAttribute((const void*)node_gemm<1, 1, 0>,
                              hipFuncAttributeMaxDynamicSharedMemorySize, 65536);
    (void)hipFuncSetAttribute((const void*)node_gemm<2, 0, 1>,
                              hipFuncAttributeMaxDynamicSharedMemorySize, 65536);

    (void)hipMemsetAsync(agg, 0, (size_t)N_NODES * 256 * sizeof(float), stream);
    (void)hipMemsetAsync(hist, 0, (size_t)N_NODES * sizeof(int), stream);

    const dim3 blk(256);
    const int mt = (N_NODES + 127) / 128;   // 196 row-tiles
    const int eb = (N_EDGES + 255) / 256;   // 1563 blocks

    // x = bf16(h @ lin1_w)
    node_gemm<0, 1, 0><<<dim3(mt * 2), blk, 65536, stream>>>(h, lin1_w, nullptr, xb, N_NODES);

    // counting sort by col + per-edge meta (d, C, r, c) + fused pos copy
    hist_kernel<<<dim3(eb), blk, 0, stream>>>(ei, hist);
    scan_kernel<<<dim3(1), dim3(1024), 0, stream>>>(hist);
    scatter_meta<<<dim3(eb), blk, 0, stream>>>(ei, pos, hist, meta, out + N_NODES * 256);

    // fused edge pipeline -> agg
    edge_kernel<<<dim3(512), blk, 81920, stream>>>(meta, mlp_w1, mlp_b1,
                                                   mlp_w2, mlp_b2, xb, agg);

    // x2 = bf16(ssp(agg @ lin2_w + lin2_b))  (reuses xb; x dead by now)
    node_gemm<1, 1, 0><<<dim3(mt * 2), blk, 65536, stream>>>(agg, lin2_w, lin2_b, xb, N_NODES);
    // h_update = x2 @ lin_w + lin_b
    node_gemm<2, 0, 1><<<dim3(mt * 2), blk, 65536, stream>>>(xb, lin_w, lin_b, out, N_NODES);
}

// Round 16
// 447.156 us; speedup vs baseline: 1.4656x; 1.0845x over previous
//
#include <hip/hip_runtime.h>
#include <hip/hip_bf16.h>

#define N_NODES 25000
#define N_EDGES 400000
#define NTILES (N_EDGES / 32)   // 12500 exact

typedef __attribute__((ext_vector_type(8))) __bf16 bf16x8;
typedef __attribute__((ext_vector_type(4))) float f32x4;
typedef __attribute__((ext_vector_type(2))) unsigned uint32x2;

// Raw workgroup barrier that does NOT drain vmcnt: waits only LDS ops.
#define BAR() do {                                          \
    asm volatile("s_waitcnt lgkmcnt(0)" ::: "memory");      \
    __builtin_amdgcn_s_barrier();                           \
    asm volatile("" ::: "memory");                          \
} while (0)

static __device__ __forceinline__ unsigned short bfbits(float f) {
    __bf16 h = (__bf16)f;
    return __builtin_bit_cast(unsigned short, h);
}
static __device__ __forceinline__ float bf2f(unsigned short u) {
    return __builtin_bit_cast(float, ((unsigned)u) << 16);
}
static __device__ __forceinline__ float ssp_f(float x) {
    const float t = __builtin_amdgcn_exp2f(x * 1.44269504f);
    return 0.69314718f * (__builtin_amdgcn_logf(1.f + t) - 1.f);
}

// ---------------------------------------------------------------------------
// out[M x 256] = op(A[M x 256] @ B[256 x 256] (+ bias))  (unchanged)
// ---------------------------------------------------------------------------
template<int EPI, int OBF, int ABF>
__global__ __launch_bounds__(256, 2)
void node_gemm(const void* __restrict__ Av, const float* __restrict__ B,
               const float* __restrict__ bias, void* __restrict__ outv, int M)
{
    extern __shared__ char lds[];
    const int tid  = threadIdx.x;
    const int half = blockIdx.x & 1;
    const int jblk = half << 7;
    const int row0 = (blockIdx.x >> 1) << 7;

    {
        const int j   = tid & 127;
        const int k2b = (tid >> 7) << 6;
        for (int i = 0; i < 64; ++i) {
            const int k = (k2b + i) * 2;
            const float b0 = B[k * 256 + jblk + j];
            const float b1 = B[(k + 1) * 256 + jblk + j];
            const unsigned pack = (unsigned)bfbits(b0) | ((unsigned)bfbits(b1) << 16);
            *(unsigned*)(lds + ((j * 512 + k * 2) ^ ((j & 7) << 4))) = pack;
        }
    }
    __syncthreads();

    const int wave = tid >> 6;
    const int l    = tid & 63;
    const int lrow = l & 15;
    const int kg   = (l >> 4) << 3;

    f32x4 acc[8][2];
    const f32x4 z4 = {0.f, 0.f, 0.f, 0.f};
    #pragma unroll
    for (int m = 0; m < 8; ++m) { acc[m][0] = z4; acc[m][1] = z4; }

    #pragma unroll
    for (int ks = 0; ks < 8; ++ks) {
        const int k0 = (ks << 5) + kg;
        bf16x8 bfr[2];
        #pragma unroll
        for (int n = 0; n < 2; ++n) {
            const int jl = (wave << 5) + (n << 4) + lrow;
            bfr[n] = *(const bf16x8*)(lds + ((jl * 512 + k0 * 2) ^ ((jl & 7) << 4)));
        }
        #pragma unroll
        for (int m = 0; m < 8; ++m) {
            const int row = row0 + (m << 4) + lrow;
            bf16x8 af;
            if (row < M) {
                if (ABF) {
                    af = *(const bf16x8*)((const __bf16*)Av + row * 256 + k0);
                } else {
                    const float* ap = (const float*)Av + row * 256 + k0;
                    const f32x4 a0 = *(const f32x4*)(ap);
                    const f32x4 a1 = *(const f32x4*)(ap + 4);
                    #pragma unroll
                    for (int b = 0; b < 4; ++b) { af[b] = (__bf16)a0[b]; af[b + 4] = (__bf16)a1[b]; }
                }
            } else {
                #pragma unroll
                for (int b = 0; b < 8; ++b) af[b] = (__bf16)0.f;
            }
            acc[m][0] = __builtin_amdgcn_mfma_f32_16x16x32_bf16(af, bfr[0], acc[m][0], 0, 0, 0);
            acc[m][1] = __builtin_amdgcn_mfma_f32_16x16x32_bf16(af, bfr[1], acc[m][1], 0, 0, 0);
        }
    }

    #pragma unroll
    for (int m = 0; m < 8; ++m) {
        #pragma unroll
        for (int n = 0; n < 2; ++n) {
            const int j = jblk + (wave << 5) + (n << 4) + lrow;
            float bv = 0.f;
            if (EPI) bv = bias[j];
            #pragma unroll
            for (int r = 0; r < 4; ++r) {
                const int row = row0 + (m << 4) + ((l >> 4) << 2) + r;
                if (row < M) {
                    float v = acc[m][n][r] + bv;
                    if (EPI == 1) v = ssp_f(v);
                    if (OBF) ((unsigned short*)outv)[row * 256 + j] = bfbits(v);
                    else     ((float*)outv)[row * 256 + j] = v;
                }
            }
        }
    }
}

// ---------------------------------------------------------------------------
// Counting sort + meta precompute + fused pos copy (unchanged)
// ---------------------------------------------------------------------------
__global__ void hist_kernel(const int* __restrict__ ei, int* __restrict__ hist)
{
    const int i = blockIdx.x * 256 + threadIdx.x;
    if (i < N_EDGES) atomicAdd(&hist[ei[N_EDGES + i]], 1);
}

__global__ void scan_kernel(int* __restrict__ hist)
{
    __shared__ int part[1024];
    const int t  = threadIdx.x;
    const int CH = (N_NODES + 1023) / 1024;   // 25
    const int lo = t * CH;
    const int hi = (lo + CH < N_NODES) ? lo + CH : N_NODES;
    int s = 0;
    for (int i = lo; i < hi; ++i) s += hist[i];
    part[t] = s;
    __syncthreads();
    for (int off = 1; off < 1024; off <<= 1) {
        const int v = part[t];
        const int u = (t >= off) ? part[t - off] : 0;
        __syncthreads();
        part[t] = v + u;
        __syncthreads();
    }
    int base = (t == 0) ? 0 : part[t - 1];
    for (int i = lo; i < hi; ++i) { const int v = hist[i]; hist[i] = base; base += v; }
}

__global__ void scatter_meta(const int* __restrict__ ei, const float* __restrict__ pos,
                             int* __restrict__ hist, float4* __restrict__ meta,
                             float* __restrict__ out_pos)
{
    const int i = blockIdx.x * 256 + threadIdx.x;
    if (i >= N_EDGES) return;
    if (i < N_NODES * 3) out_pos[i] = pos[i];
    const int r = ei[i];
    const int c = ei[N_EDGES + i];
    const float dx = pos[r * 3 + 0] - pos[c * 3 + 0];
    const float dy = pos[r * 3 + 1] - pos[c * 3 + 1];
    const float dz = pos[r * 3 + 2] - pos[c * 3 + 2];
    const float d  = __fsqrt_rn(dx * dx + dy * dy + dz * dz);
    const float C  = 0.5f * (__cosf(d * 0.31415926535f) + 1.f);
    const int p = atomicAdd(&hist[c], 1);
    float4 m;
    m.x = d; m.y = C;
    m.z = __int_as_float(r); m.w = __int_as_float(c);
    meta[p] = m;
}

// ---------------------------------------------------------------------------
// Fused edge kernel over SORTED edges — R13 base (measured 269us),
// R16 delta: gs region moved to rb[12K:16K], DISJOINT from ms[0:8K] and
// colsm[8192:8320] -> the gauss write no longer races the reader -> B1
// eliminated, 5 barriers/tile:
//   gauss->gs | B2 gs ready | GEMM1 | B3 gs reads done -> tb writable |
//   ssp->tb | B4 tb ready | GEMM2 | B5 tb reads done -> ms writable |
//   msg+colsm | B6 ms ready | reader
// Cross-tile: gauss write (after B6) vs prev GEMM2 tb-reads (before B5): 2
// barriers apart ✓; vs prev ssp writes (before B4): 3 apart ✓.
// ---------------------------------------------------------------------------
__global__ __launch_bounds__(256, 2)
void edge_kernel(const float4* __restrict__ meta,
                 const float* __restrict__ w1, const float* __restrict__ b1,
                 const float* __restrict__ w2, const float* __restrict__ b2,
                 const unsigned short* __restrict__ xb, float* __restrict__ agg)
{
    extern __shared__ char lds[];
    char* w2t = lds;
    char* rb  = lds + 65536;          // tb = rb[0:16K]; ms = rb[0:8K]
    char* gsp = rb + 12288;           // gs = rb[12K:16K] (disjoint from ms+colsm)
    int* colsm = (int*)(rb + 8192);

    const int tid   = threadIdx.x;
    const int wave  = tid >> 6;
    const int l     = tid & 63;
    const int lrow  = l & 15;
    const int g     = l >> 4;
    const int kg    = g << 3;
    const int half  = blockIdx.x & 1;
    const int jblk  = half << 7;
    const int group = blockIdx.x >> 1;

    // stage W2^T half
    {
        const int j   = tid & 127;
        const int k2b = (tid >> 7) << 6;
        for (int i = 0; i < 64; ++i) {
            const int k = (k2b + i) * 2;
            const float v0 = w2[k * 256 + jblk + j];
            const float v1 = w2[(k + 1) * 256 + jblk + j];
            const unsigned pack = (unsigned)bfbits(v0) | ((unsigned)bfbits(v1) << 16);
            *(unsigned*)(w2t + ((j * 512 + k * 2) ^ ((j & 7) << 4))) = pack;
        }
    }

    // W1 B-fragments in registers (wave owns 64 filter cols)
    const float dlt    = 10.f / 49.f;
    const float coeff2 = (-0.5f / (dlt * dlt)) * 1.44269504f;   // log2e folded
    bf16x8 w1f[4][2];
    #pragma unroll
    for (int n = 0; n < 4; ++n)
        #pragma unroll
        for (int ks = 0; ks < 2; ++ks) {
            bf16x8 v;
            #pragma unroll
            for (int b = 0; b < 8; ++b) {
                const int k = (ks << 5) + kg + b;
                const int j = (wave << 6) + (n << 4) + lrow;
                v[b] = (k < 50) ? (__bf16)w1[k * 256 + j] : (__bf16)0.f;
            }
            w1f[n][ks] = v;
        }
    float b1v[4], b2v[2];
    #pragma unroll
    for (int n = 0; n < 4; ++n) b1v[n] = b1[(wave << 6) + (n << 4) + lrow];
    #pragma unroll
    for (int n = 0; n < 2; ++n) b2v[n] = b2[jblk + (wave << 5) + (n << 4) + lrow];

    BAR();   // w2t ready

    const f32x4 z4 = {0.f, 0.f, 0.f, 0.f};
    const int CH = (NTILES + 255) / 256;    // 49 tiles per group, contiguous
    const int t0 = group * CH;
    int t1 = t0 + CH; if (t1 > NTILES) t1 = NTILES;

    const int ge  = tid >> 3;         // gaussian producer: edge 0..31
    const int gkb = (tid & 7) << 3;   // gaussian producer: k-base

    // reader run-carry state (used by tid < 128 only)
    int   rprev  = -1;
    float rs     = 0.f;
    int   rfirst = 1;
    float* aj    = agg + jblk + (tid & 127);

    // meta prefetch
    float4 mv = meta[(t0 << 5) + (l & 31)];

    for (int t = t0; t < t1; ++t) {
        const float d  = mv.x;
        const float Cc = mv.y;
        const int   r  = __float_as_int(mv.z);
        const int   c  = __float_as_int(mv.w);
        if (t + 1 < t1) mv = meta[((t + 1) << 5) + (l & 31)];

        // hoisted bf16 x-gather (in flight until msg epilogue)
        float xv[2][2][4];
        #pragma unroll
        for (int m = 0; m < 2; ++m)
            #pragma unroll
            for (int r4 = 0; r4 < 4; ++r4) {
                const int e  = (m << 4) + (g << 2) + r4;
                const int re = __shfl(r, e, 64);
                #pragma unroll
                for (int n = 0; n < 2; ++n) {
                    const int jloc = (wave << 5) + (n << 4) + lrow;
                    xv[m][n][r4] = bf2f(xb[re * 256 + jblk + jloc]);
                }
            }

        // gaussian producer: thread (ge, gkb) computes 8 k-values for edge ge
        const float gd = __shfl(d, ge, 64);
        bf16x8 gv;
        #pragma unroll
        for (int b = 0; b < 8; ++b) {
            const int k = gkb + b;
            float gval = 0.f;
            if (k < 50) {
                const float u = gd - (float)k * dlt;
                gval = __builtin_amdgcn_exp2f(coeff2 * u * u);
            }
            gv[b] = (__bf16)gval;
        }
        // gs disjoint from reader's ms+colsm -> no pre-write barrier needed
        *(bf16x8*)(gsp + ((ge * 128 + (gkb << 1)) ^ ((ge & 7) << 4))) = gv;
        BAR();   // B2: gaussians visible

        // ---- GEMM1: gauss[32][64] @ W1 -> acc1 (wave owns 64 filter cols)
        bf16x8 af[2][2];
        #pragma unroll
        for (int m = 0; m < 2; ++m) {
            const int e = (m << 4) + lrow;
            #pragma unroll
            for (int ks = 0; ks < 2; ++ks)
                af[m][ks] = *(const bf16x8*)(gsp + ((e * 128 + ((ks << 5) + kg) * 2) ^ ((e & 7) << 4)));
        }
        f32x4 acc1[2][4];
        #pragma unroll
        for (int m = 0; m < 2; ++m)
            #pragma unroll
            for (int n = 0; n < 4; ++n) acc1[m][n] = z4;
        #pragma unroll
        for (int ks = 0; ks < 2; ++ks)
            #pragma unroll
            for (int m = 0; m < 2; ++m)
                #pragma unroll
                for (int n = 0; n < 4; ++n)
                    acc1[m][n] = __builtin_amdgcn_mfma_f32_16x16x32_bf16(af[m][ks], w1f[n][ks], acc1[m][n], 0, 0, 0);
        BAR();   // B3: gs reads done; tb region writable

        // ---- epilogue1: t = ssp(acc1 + b1) -> tb bf16 (swizzled)
        #pragma unroll
        for (int m = 0; m < 2; ++m)
            #pragma unroll
            for (int n = 0; n < 4; ++n)
                #pragma unroll
                for (int r4 = 0; r4 < 4; ++r4) {
                    const int e = (m << 4) + (g << 2) + r4;
                    const int k = (wave << 6) + (n << 4) + lrow;
                    const float v = ssp_f(acc1[m][n][r4] + b1v[n]);
                    *(__bf16*)(rb + ((e * 512 + k * 2) ^ ((e & 7) << 4))) = (__bf16)v;
                }
        BAR();   // B4: tb ready

        // ---- GEMM2: t[32][256] @ W2[:, jblk:+128] -> acc2
        f32x4 acc2[2][2];
        #pragma unroll
        for (int m = 0; m < 2; ++m) { acc2[m][0] = z4; acc2[m][1] = z4; }
        #pragma unroll
        for (int ks = 0; ks < 8; ++ks) {
            const int k0 = (ks << 5) + kg;
            bf16x8 bfr[2];
            #pragma unroll
            for (int n = 0; n < 2; ++n) {
                const int jl = (wave << 5) + (n << 4) + lrow;
                bfr[n] = *(const bf16x8*)(w2t + ((jl * 512 + k0 * 2) ^ ((jl & 7) << 4)));
            }
            #pragma unroll
            for (int m = 0; m < 2; ++m) {
                const int e = (m << 4) + lrow;
                const bf16x8 a = *(const bf16x8*)(rb + ((e * 512 + k0 * 2) ^ ((e & 7) << 4)));
                #pragma unroll
                for (int n = 0; n < 2; ++n)
                    acc2[m][n] = __builtin_amdgcn_mfma_f32_16x16x32_bf16(a, bfr[n], acc2[m][n], 0, 0, 0);
            }
        }
        BAR();   // B5: tb reads done; ms region writable

        // ---- msg epilogue: (acc2+b2)*C * xv -> ms[j][e] bf16 (swizzled)
        #pragma unroll
        for (int m = 0; m < 2; ++m) {
            const int base_e = (m << 4) + (g << 2);
            #pragma unroll
            for (int n = 0; n < 2; ++n) {
                const int jloc = (wave << 5) + (n << 4) + lrow;
                float vv[4];
                #pragma unroll
                for (int r4 = 0; r4 < 4; ++r4) {
                    const int e  = base_e + r4;
                    const float Ce = __shfl(Cc, e, 64);
                    vv[r4] = (acc2[m][n][r4] + b2v[n]) * Ce * xv[m][n][r4];
                }
                uint32x2 pk;
                pk[0] = (unsigned)bfbits(vv[0]) | ((unsigned)bfbits(vv[1]) << 16);
                pk[1] = (unsigned)bfbits(vv[2]) | ((unsigned)bfbits(vv[3]) << 16);
                *(uint32x2*)(rb + ((jloc * 64 + (base_e << 1)) ^ ((jloc & 7) << 4))) = pk;
            }
        }
        if (tid < 32) colsm[tid] = c;
        BAR();   // B6: ms + colsm ready

        // ---- reader: 128 threads, one j each, 32 edges; run-carry reduce
        if (tid < 128) {
            const int j = tid;
            const bf16x8 q0 = *(const bf16x8*)(rb + ((j * 64 +  0) ^ ((j & 7) << 4)));
            const bf16x8 q1 = *(const bf16x8*)(rb + ((j * 64 + 16) ^ ((j & 7) << 4)));
            const bf16x8 q2 = *(const bf16x8*)(rb + ((j * 64 + 32) ^ ((j & 7) << 4)));
            const bf16x8 q3 = *(const bf16x8*)(rb + ((j * 64 + 48) ^ ((j & 7) << 4)));
            #pragma unroll
            for (int e = 0; e < 32; ++e) {
                const float v = (float)(e < 8 ? q0[e] : e < 16 ? q1[e - 8] :
                                        e < 24 ? q2[e - 16] : q3[e - 24]);
                const int ce = colsm[e];
                if (ce != rprev) {                    // wave-uniform branch
                    if (rprev >= 0) {
                        if (rfirst) { atomicAdd(aj + rprev * 256, rs); rfirst = 0; }
                        else        { aj[rprev * 256] = rs; }
                    }
                    rs = 0.f; rprev = ce;
                }
                rs += v;
            }
        }
    }
    // final flush: run may continue into the next chunk -> atomic
    if (tid < 128 && rprev >= 0) atomicAdd(aj + rprev * 256, rs);
}

extern "C" void kernel_launch(void* const* d_in, const int* in_sizes, int n_in,
                              void* d_out, int out_size, void* d_ws, size_t ws_size,
                              hipStream_t stream)
{
    const float* h      = (const float*)d_in[0];
    const float* pos    = (const float*)d_in[1];
    const float* lin1_w = (const float*)d_in[2];
    const float* lin2_w = (const float*)d_in[3];
    const float* lin2_b = (const float*)d_in[4];
    const float* mlp_w1 = (const float*)d_in[5];
    const float* mlp_b1 = (const float*)d_in[6];
    const float* mlp_w2 = (const float*)d_in[7];
    const float* mlp_b2 = (const float*)d_in[8];
    const float* lin_w  = (const float*)d_in[9];
    const float* lin_b  = (const float*)d_in[10];
    const int*   ei     = (const int*)d_in[11];
    float* out = (float*)d_out;

    // ws layout: xb bf16 12.8M | agg 25.6M | meta 6.4M | hist 0.1M
    unsigned short* xb  = (unsigned short*)d_ws;
    float*  agg  = (float*)((char*)d_ws + 12800000);
    float4* meta = (float4*)((char*)d_ws + 38400000);
    int*    hist = (int*)((char*)d_ws + 44800000);

    (void)hipFuncSetAttribute((const void*)edge_kernel,
                              hipFuncAttributeMaxDynamicSharedMemorySize, 81920);
    (void)hipFuncSetAttribute((const void*)node_gemm<0, 1, 0>,
                              hipFuncAttributeMaxDynamicSharedMemorySize, 65536);
    (void)hipFuncSetAttribute((const void*)node_gemm<1, 1, 0>,
                              hipFuncAttributeMaxDynamicSharedMemorySize, 65536);
    (void)hipFuncSetAttribute((const void*)node_gemm<2, 0, 1>,
                              hipFuncAttributeMaxDynamicSharedMemorySize, 65536);

    (void)hipMemsetAsync(agg, 0, (size_t)N_NODES * 256 * sizeof(float), stream);
    (void)hipMemsetAsync(hist, 0, (size_t)N_NODES * sizeof(int), stream);

    const dim3 blk(256);
    const int mt = (N_NODES + 127) / 128;   // 196 row-tiles
    const int eb = (N_EDGES + 255) / 256;   // 1563 blocks

    // x = bf16(h @ lin1_w)
    node_gemm<0, 1, 0><<<dim3(mt * 2), blk, 65536, stream>>>(h, lin1_w, nullptr, xb, N_NODES);

    // counting sort by col + per-edge meta (d, C, r, c) + fused pos copy
    hist_kernel<<<dim3(eb), blk, 0, stream>>>(ei, hist);
    scan_kernel<<<dim3(1), dim3(1024), 0, stream>>>(hist);
    scatter_meta<<<dim3(eb), blk, 0, stream>>>(ei, pos, hist, meta, out + N_NODES * 256);

    // fused edge pipeline -> agg
    edge_kernel<<<dim3(512), blk, 81920, stream>>>(meta, mlp_w1, mlp_b1,
                                                   mlp_w2, mlp_b2, xb, agg);

    // x2 = bf16(ssp(agg @ lin2_w + lin2_b))  (reuses xb; x dead by now)
    node_gemm<1, 1, 0><<<dim3(mt * 2), blk, 65536, stream>>>(agg, lin2_w, lin2_b, xb, N_NODES);
    // h_update = x2 @ lin_w + lin_b
    node_gemm<2, 0, 1><<<dim3(mt * 2), blk, 65536, stream>>>(xb, lin_w, lin_b, out, N_NODES);
}

// Round 17
// 420.437 us; speedup vs baseline: 1.5587x; 1.0636x over previous
//
#include <hip/hip_runtime.h>
#include <hip/hip_bf16.h>

#define N_NODES 25000
#define N_EDGES 400000
#define NTILES (N_EDGES / 32)   // 12500 exact

typedef __attribute__((ext_vector_type(8))) __bf16 bf16x8;
typedef __attribute__((ext_vector_type(4))) float f32x4;
typedef __attribute__((ext_vector_type(2))) unsigned uint32x2;

// Raw workgroup barrier that does NOT drain vmcnt: waits only LDS ops.
#define BAR() do {                                          \
    asm volatile("s_waitcnt lgkmcnt(0)" ::: "memory");      \
    __builtin_amdgcn_s_barrier();                           \
    asm volatile("" ::: "memory");                          \
} while (0)

static __device__ __forceinline__ unsigned short bfbits(float f) {
    __bf16 h = (__bf16)f;
    return __builtin_bit_cast(unsigned short, h);
}
static __device__ __forceinline__ float bf2f(unsigned short u) {
    return __builtin_bit_cast(float, ((unsigned)u) << 16);
}
static __device__ __forceinline__ float ssp_f(float x) {
    const float t = __builtin_amdgcn_exp2f(x * 1.44269504f);
    return 0.69314718f * (__builtin_amdgcn_logf(1.f + t) - 1.f);
}

// ---------------------------------------------------------------------------
// Transpose+convert the three 256x256 f32 weight matrices to bf16 B^T once.
// ---------------------------------------------------------------------------
__global__ void convt_kernel(const float* __restrict__ b0, const float* __restrict__ b1,
                             const float* __restrict__ b2, __bf16* __restrict__ t0,
                             __bf16* __restrict__ t1, __bf16* __restrict__ t2)
{
    const int i   = blockIdx.x * 256 + threadIdx.x;   // 0..196607
    const int mat = i >> 16;
    const int e   = i & 65535;
    const int k   = e >> 8;
    const int j   = e & 255;
    const float* src = (mat == 0) ? b0 : (mat == 1) ? b1 : b2;
    __bf16*      dst = (mat == 0) ? t0 : (mat == 1) ? t1 : t2;
    dst[j * 256 + k] = (__bf16)src[k * 256 + j];
}

// ---------------------------------------------------------------------------
// out[M x 256] = op(A[M x 256] @ B[256 x 256] (+ bias)), B given as bf16 B^T.
// LDS-FREE: B-frags read directly from global (B^T is 128KB, L2-resident).
// Block = 64 rows x 256 cols; wave owns 64 cols (acc[4][4]). No barriers.
// EPI: 0 none, 1 ssp(v+bias), 2 v+bias. OBF: bf16 out. ABF: bf16 A.
// ---------------------------------------------------------------------------
template<int EPI, int OBF, int ABF>
__global__ __launch_bounds__(256, 2)
void node_gemm(const void* __restrict__ Av, const __bf16* __restrict__ Bt,
               const float* __restrict__ bias, void* __restrict__ outv, int M)
{
    const int tid  = threadIdx.x;
    const int wave = tid >> 6;
    const int l    = tid & 63;
    const int lrow = l & 15;
    const int kg   = (l >> 4) << 3;
    const int row0 = blockIdx.x << 6;
    const int jw   = wave << 6;

    f32x4 acc[4][4];
    const f32x4 z4 = {0.f, 0.f, 0.f, 0.f};
    #pragma unroll
    for (int m = 0; m < 4; ++m)
        #pragma unroll
        for (int n = 0; n < 4; ++n) acc[m][n] = z4;

    #pragma unroll
    for (int ks = 0; ks < 8; ++ks) {
        const int k0 = (ks << 5) + kg;
        bf16x8 bfr[4];
        #pragma unroll
        for (int n = 0; n < 4; ++n) {
            const int jl = jw + (n << 4) + lrow;
            bfr[n] = *(const bf16x8*)(Bt + jl * 256 + k0);
        }
        #pragma unroll
        for (int m = 0; m < 4; ++m) {
            const int row = row0 + (m << 4) + lrow;
            bf16x8 af;
            if (row < M) {
                if (ABF) {
                    af = *(const bf16x8*)((const __bf16*)Av + row * 256 + k0);
                } else {
                    const float* ap = (const float*)Av + row * 256 + k0;
                    const f32x4 a0 = *(const f32x4*)(ap);
                    const f32x4 a1 = *(const f32x4*)(ap + 4);
                    #pragma unroll
                    for (int b = 0; b < 4; ++b) { af[b] = (__bf16)a0[b]; af[b + 4] = (__bf16)a1[b]; }
                }
            } else {
                #pragma unroll
                for (int b = 0; b < 8; ++b) af[b] = (__bf16)0.f;
            }
            #pragma unroll
            for (int n = 0; n < 4; ++n)
                acc[m][n] = __builtin_amdgcn_mfma_f32_16x16x32_bf16(af, bfr[n], acc[m][n], 0, 0, 0);
        }
    }

    #pragma unroll
    for (int m = 0; m < 4; ++m) {
        #pragma unroll
        for (int n = 0; n < 4; ++n) {
            const int j = jw + (n << 4) + lrow;
            float bv = 0.f;
            if (EPI) bv = bias[j];
            #pragma unroll
            for (int r = 0; r < 4; ++r) {
                const int row = row0 + (m << 4) + ((l >> 4) << 2) + r;
                if (row < M) {
                    float v = acc[m][n][r] + bv;
                    if (EPI == 1) v = ssp_f(v);
                    if (OBF) ((unsigned short*)outv)[row * 256 + j] = bfbits(v);
                    else     ((float*)outv)[row * 256 + j] = v;
                }
            }
        }
    }
}

// ---------------------------------------------------------------------------
// Counting sort + meta precompute + fused pos copy (unchanged)
// ---------------------------------------------------------------------------
__global__ void hist_kernel(const int* __restrict__ ei, int* __restrict__ hist)
{
    const int i = blockIdx.x * 256 + threadIdx.x;
    if (i < N_EDGES) atomicAdd(&hist[ei[N_EDGES + i]], 1);
}

__global__ void scan_kernel(int* __restrict__ hist)
{
    __shared__ int part[1024];
    const int t  = threadIdx.x;
    const int CH = (N_NODES + 1023) / 1024;   // 25
    const int lo = t * CH;
    const int hi = (lo + CH < N_NODES) ? lo + CH : N_NODES;
    int s = 0;
    for (int i = lo; i < hi; ++i) s += hist[i];
    part[t] = s;
    __syncthreads();
    for (int off = 1; off < 1024; off <<= 1) {
        const int v = part[t];
        const int u = (t >= off) ? part[t - off] : 0;
        __syncthreads();
        part[t] = v + u;
        __syncthreads();
    }
    int base = (t == 0) ? 0 : part[t - 1];
    for (int i = lo; i < hi; ++i) { const int v = hist[i]; hist[i] = base; base += v; }
}

__global__ void scatter_meta(const int* __restrict__ ei, const float* __restrict__ pos,
                             int* __restrict__ hist, float4* __restrict__ meta,
                             float* __restrict__ out_pos)
{
    const int i = blockIdx.x * 256 + threadIdx.x;
    if (i >= N_EDGES) return;
    if (i < N_NODES * 3) out_pos[i] = pos[i];
    const int r = ei[i];
    const int c = ei[N_EDGES + i];
    const float dx = pos[r * 3 + 0] - pos[c * 3 + 0];
    const float dy = pos[r * 3 + 1] - pos[c * 3 + 1];
    const float dz = pos[r * 3 + 2] - pos[c * 3 + 2];
    const float d  = __fsqrt_rn(dx * dx + dy * dy + dz * dz);
    const float C  = 0.5f * (__cosf(d * 0.31415926535f) + 1.f);
    const int p = atomicAdd(&hist[c], 1);
    float4 m;
    m.x = d; m.y = C;
    m.z = __int_as_float(r); m.w = __int_as_float(c);
    meta[p] = m;
}

// ---------------------------------------------------------------------------
// Fused edge kernel — byte-identical to R16 (measured 269us, tied-best).
// ---------------------------------------------------------------------------
__global__ __launch_bounds__(256, 2)
void edge_kernel(const float4* __restrict__ meta,
                 const float* __restrict__ w1, const float* __restrict__ b1,
                 const float* __restrict__ w2, const float* __restrict__ b2,
                 const unsigned short* __restrict__ xb, float* __restrict__ agg)
{
    extern __shared__ char lds[];
    char* w2t = lds;
    char* rb  = lds + 65536;          // tb = rb[0:16K]; ms = rb[0:8K]
    char* gsp = rb + 12288;           // gs = rb[12K:16K] (disjoint from ms+colsm)
    int* colsm = (int*)(rb + 8192);

    const int tid   = threadIdx.x;
    const int wave  = tid >> 6;
    const int l     = tid & 63;
    const int lrow  = l & 15;
    const int g     = l >> 4;
    const int kg    = g << 3;
    const int half  = blockIdx.x & 1;
    const int jblk  = half << 7;
    const int group = blockIdx.x >> 1;

    // stage W2^T half
    {
        const int j   = tid & 127;
        const int k2b = (tid >> 7) << 6;
        for (int i = 0; i < 64; ++i) {
            const int k = (k2b + i) * 2;
            const float v0 = w2[k * 256 + jblk + j];
            const float v1 = w2[(k + 1) * 256 + jblk + j];
            const unsigned pack = (unsigned)bfbits(v0) | ((unsigned)bfbits(v1) << 16);
            *(unsigned*)(w2t + ((j * 512 + k * 2) ^ ((j & 7) << 4))) = pack;
        }
    }

    // W1 B-fragments in registers (wave owns 64 filter cols)
    const float dlt    = 10.f / 49.f;
    const float coeff2 = (-0.5f / (dlt * dlt)) * 1.44269504f;   // log2e folded
    bf16x8 w1f[4][2];
    #pragma unroll
    for (int n = 0; n < 4; ++n)
        #pragma unroll
        for (int ks = 0; ks < 2; ++ks) {
            bf16x8 v;
            #pragma unroll
            for (int b = 0; b < 8; ++b) {
                const int k = (ks << 5) + kg + b;
                const int j = (wave << 6) + (n << 4) + lrow;
                v[b] = (k < 50) ? (__bf16)w1[k * 256 + j] : (__bf16)0.f;
            }
            w1f[n][ks] = v;
        }
    float b1v[4], b2v[2];
    #pragma unroll
    for (int n = 0; n < 4; ++n) b1v[n] = b1[(wave << 6) + (n << 4) + lrow];
    #pragma unroll
    for (int n = 0; n < 2; ++n) b2v[n] = b2[jblk + (wave << 5) + (n << 4) + lrow];

    BAR();   // w2t ready

    const f32x4 z4 = {0.f, 0.f, 0.f, 0.f};
    const int CH = (NTILES + 255) / 256;    // 49 tiles per group, contiguous
    const int t0 = group * CH;
    int t1 = t0 + CH; if (t1 > NTILES) t1 = NTILES;

    const int ge  = tid >> 3;         // gaussian producer: edge 0..31
    const int gkb = (tid & 7) << 3;   // gaussian producer: k-base

    // reader run-carry state (used by tid < 128 only)
    int   rprev  = -1;
    float rs     = 0.f;
    int   rfirst = 1;
    float* aj    = agg + jblk + (tid & 127);

    // meta prefetch
    float4 mv = meta[(t0 << 5) + (l & 31)];

    for (int t = t0; t < t1; ++t) {
        const float d  = mv.x;
        const float Cc = mv.y;
        const int   r  = __float_as_int(mv.z);
        const int   c  = __float_as_int(mv.w);
        if (t + 1 < t1) mv = meta[((t + 1) << 5) + (l & 31)];

        // hoisted bf16 x-gather (in flight until msg epilogue)
        float xv[2][2][4];
        #pragma unroll
        for (int m = 0; m < 2; ++m)
            #pragma unroll
            for (int r4 = 0; r4 < 4; ++r4) {
                const int e  = (m << 4) + (g << 2) + r4;
                const int re = __shfl(r, e, 64);
                #pragma unroll
                for (int n = 0; n < 2; ++n) {
                    const int jloc = (wave << 5) + (n << 4) + lrow;
                    xv[m][n][r4] = bf2f(xb[re * 256 + jblk + jloc]);
                }
            }

        // gaussian producer: thread (ge, gkb) computes 8 k-values for edge ge
        const float gd = __shfl(d, ge, 64);
        bf16x8 gv;
        #pragma unroll
        for (int b = 0; b < 8; ++b) {
            const int k = gkb + b;
            float gval = 0.f;
            if (k < 50) {
                const float u = gd - (float)k * dlt;
                gval = __builtin_amdgcn_exp2f(coeff2 * u * u);
            }
            gv[b] = (__bf16)gval;
        }
        // gs disjoint from reader's ms+colsm -> no pre-write barrier needed
        *(bf16x8*)(gsp + ((ge * 128 + (gkb << 1)) ^ ((ge & 7) << 4))) = gv;
        BAR();   // B2: gaussians visible

        // ---- GEMM1: gauss[32][64] @ W1 -> acc1 (wave owns 64 filter cols)
        bf16x8 af[2][2];
        #pragma unroll
        for (int m = 0; m < 2; ++m) {
            const int e = (m << 4) + lrow;
            #pragma unroll
            for (int ks = 0; ks < 2; ++ks)
                af[m][ks] = *(const bf16x8*)(gsp + ((e * 128 + ((ks << 5) + kg) * 2) ^ ((e & 7) << 4)));
        }
        f32x4 acc1[2][4];
        #pragma unroll
        for (int m = 0; m < 2; ++m)
            #pragma unroll
            for (int n = 0; n < 4; ++n) acc1[m][n] = z4;
        #pragma unroll
        for (int ks = 0; ks < 2; ++ks)
            #pragma unroll
            for (int m = 0; m < 2; ++m)
                #pragma unroll
                for (int n = 0; n < 4; ++n)
                    acc1[m][n] = __builtin_amdgcn_mfma_f32_16x16x32_bf16(af[m][ks], w1f[n][ks], acc1[m][n], 0, 0, 0);
        BAR();   // B3: gs reads done; tb region writable

        // ---- epilogue1: t = ssp(acc1 + b1) -> tb bf16 (swizzled)
        #pragma unroll
        for (int m = 0; m < 2; ++m)
            #pragma unroll
            for (int n = 0; n < 4; ++n)
                #pragma unroll
                for (int r4 = 0; r4 < 4; ++r4) {
                    const int e = (m << 4) + (g << 2) + r4;
                    const int k = (wave << 6) + (n << 4) + lrow;
                    const float v = ssp_f(acc1[m][n][r4] + b1v[n]);
                    *(__bf16*)(rb + ((e * 512 + k * 2) ^ ((e & 7) << 4))) = (__bf16)v;
                }
        BAR();   // B4: tb ready

        // ---- GEMM2: t[32][256] @ W2[:, jblk:+128] -> acc2
        f32x4 acc2[2][2];
        #pragma unroll
        for (int m = 0; m < 2; ++m) { acc2[m][0] = z4; acc2[m][1] = z4; }
        #pragma unroll
        for (int ks = 0; ks < 8; ++ks) {
            const int k0 = (ks << 5) + kg;
            bf16x8 bfr[2];
            #pragma unroll
            for (int n = 0; n < 2; ++n) {
                const int jl = (wave << 5) + (n << 4) + lrow;
                bfr[n] = *(const bf16x8*)(w2t + ((jl * 512 + k0 * 2) ^ ((jl & 7) << 4)));
            }
            #pragma unroll
            for (int m = 0; m < 2; ++m) {
                const int e = (m << 4) + lrow;
                const bf16x8 a = *(const bf16x8*)(rb + ((e * 512 + k0 * 2) ^ ((e & 7) << 4)));
                #pragma unroll
                for (int n = 0; n < 2; ++n)
                    acc2[m][n] = __builtin_amdgcn_mfma_f32_16x16x32_bf16(a, bfr[n], acc2[m][n], 0, 0, 0);
            }
        }
        BAR();   // B5: tb reads done; ms region writable

        // ---- msg epilogue: (acc2+b2)*C * xv -> ms[j][e] bf16 (swizzled)
        #pragma unroll
        for (int m = 0; m < 2; ++m) {
            const int base_e = (m << 4) + (g << 2);
            #pragma unroll
            for (int n = 0; n < 2; ++n) {
                const int jloc = (wave << 5) + (n << 4) + lrow;
                float vv[4];
                #pragma unroll
                for (int r4 = 0; r4 < 4; ++r4) {
                    const int e  = base_e + r4;
                    const float Ce = __shfl(Cc, e, 64);
                    vv[r4] = (acc2[m][n][r4] + b2v[n]) * Ce * xv[m][n][r4];
                }
                uint32x2 pk;
                pk[0] = (unsigned)bfbits(vv[0]) | ((unsigned)bfbits(vv[1]) << 16);
                pk[1] = (unsigned)bfbits(vv[2]) | ((unsigned)bfbits(vv[3]) << 16);
                *(uint32x2*)(rb + ((jloc * 64 + (base_e << 1)) ^ ((jloc & 7) << 4))) = pk;
            }
        }
        if (tid < 32) colsm[tid] = c;
        BAR();   // B6: ms + colsm ready

        // ---- reader: 128 threads, one j each, 32 edges; run-carry reduce
        if (tid < 128) {
            const int j = tid;
            const bf16x8 q0 = *(const bf16x8*)(rb + ((j * 64 +  0) ^ ((j & 7) << 4)));
            const bf16x8 q1 = *(const bf16x8*)(rb + ((j * 64 + 16) ^ ((j & 7) << 4)));
            const bf16x8 q2 = *(const bf16x8*)(rb + ((j * 64 + 32) ^ ((j & 7) << 4)));
            const bf16x8 q3 = *(const bf16x8*)(rb + ((j * 64 + 48) ^ ((j & 7) << 4)));
            #pragma unroll
            for (int e = 0; e < 32; ++e) {
                const float v = (float)(e < 8 ? q0[e] : e < 16 ? q1[e - 8] :
                                        e < 24 ? q2[e - 16] : q3[e - 24]);
                const int ce = colsm[e];
                if (ce != rprev) {                    // wave-uniform branch
                    if (rprev >= 0) {
                        if (rfirst) { atomicAdd(aj + rprev * 256, rs); rfirst = 0; }
                        else        { aj[rprev * 256] = rs; }
                    }
                    rs = 0.f; rprev = ce;
                }
                rs += v;
            }
        }
    }
    // final flush: run may continue into the next chunk -> atomic
    if (tid < 128 && rprev >= 0) atomicAdd(aj + rprev * 256, rs);
}

extern "C" void kernel_launch(void* const* d_in, const int* in_sizes, int n_in,
                              void* d_out, int out_size, void* d_ws, size_t ws_size,
                              hipStream_t stream)
{
    const float* h      = (const float*)d_in[0];
    const float* pos    = (const float*)d_in[1];
    const float* lin1_w = (const float*)d_in[2];
    const float* lin2_w = (const float*)d_in[3];
    const float* lin2_b = (const float*)d_in[4];
    const float* mlp_w1 = (const float*)d_in[5];
    const float* mlp_b1 = (const float*)d_in[6];
    const float* mlp_w2 = (const float*)d_in[7];
    const float* mlp_b2 = (const float*)d_in[8];
    const float* lin_w  = (const float*)d_in[9];
    const float* lin_b  = (const float*)d_in[10];
    const int*   ei     = (const int*)d_in[11];
    float* out = (float*)d_out;

    // ws layout: xb bf16 12.8M | agg 25.6M | meta 6.4M | hist 0.1M | Bt x3
    unsigned short* xb  = (unsigned short*)d_ws;
    float*  agg  = (float*)((char*)d_ws + 12800000);
    float4* meta = (float4*)((char*)d_ws + 38400000);
    int*    hist = (int*)((char*)d_ws + 44800000);
    __bf16* bt0  = (__bf16*)((char*)d_ws + 44900000);   // 131072 B each
    __bf16* bt1  = bt0 + 65536;
    __bf16* bt2  = bt1 + 65536;

    (void)hipFuncSetAttribute((const void*)edge_kernel,
                              hipFuncAttributeMaxDynamicSharedMemorySize, 81920);

    (void)hipMemsetAsync(agg, 0, (size_t)N_NODES * 256 * sizeof(float), stream);
    (void)hipMemsetAsync(hist, 0, (size_t)N_NODES * sizeof(int), stream);

    const dim3 blk(256);
    const int mt = (N_NODES + 63) / 64;     // 391 row-tiles
    const int eb = (N_EDGES + 255) / 256;   // 1563 blocks

    // one-shot B^T bf16 conversion for the three node GEMMs
    convt_kernel<<<dim3(768), blk, 0, stream>>>(lin1_w, lin2_w, lin_w, bt0, bt1, bt2);

    // x = bf16(h @ lin1_w)
    node_gemm<0, 1, 0><<<dim3(mt), blk, 0, stream>>>(h, bt0, nullptr, xb, N_NODES);

    // counting sort by col + per-edge meta (d, C, r, c) + fused pos copy
    hist_kernel<<<dim3(eb), blk, 0, stream>>>(ei, hist);
    scan_kernel<<<dim3(1), dim3(1024), 0, stream>>>(hist);
    scatter_meta<<<dim3(eb), blk, 0, stream>>>(ei, pos, hist, meta, out + N_NODES * 256);

    // fused edge pipeline -> agg
    edge_kernel<<<dim3(512), blk, 81920, stream>>>(meta, mlp_w1, mlp_b1,
                                                   mlp_w2, mlp_b2, xb, agg);

    // x2 = bf16(ssp(agg @ lin2_w + lin2_b))  (reuses xb; x dead by now)
    node_gemm<1, 1, 0><<<dim3(mt), blk, 0, stream>>>(agg, bt1, lin2_b, xb, N_NODES);
    // h_update = x2 @ lin_w + lin_b
    node_gemm<2, 0, 1><<<dim3(mt), blk, 0, stream>>>(xb, bt2, lin_b, out, N_NODES);
}

// Round 18
// 406.084 us; speedup vs baseline: 1.6138x; 1.0353x over previous
//
#include <hip/hip_runtime.h>
#include <hip/hip_bf16.h>

#define N_NODES 25000
#define N_EDGES 400000
#define NTILES (N_EDGES / 32)   // 12500 exact

typedef __attribute__((ext_vector_type(8))) __bf16 bf16x8;
typedef __attribute__((ext_vector_type(4))) float f32x4;
typedef __attribute__((ext_vector_type(2))) unsigned uint32x2;

// Raw workgroup barrier that does NOT drain vmcnt: waits only LDS ops.
#define BAR() do {                                          \
    asm volatile("s_waitcnt lgkmcnt(0)" ::: "memory");      \
    __builtin_amdgcn_s_barrier();                           \
    asm volatile("" ::: "memory");                          \
} while (0)

static __device__ __forceinline__ unsigned short bfbits(float f) {
    __bf16 h = (__bf16)f;
    return __builtin_bit_cast(unsigned short, h);
}
static __device__ __forceinline__ float bf2f(unsigned short u) {
    return __builtin_bit_cast(float, ((unsigned)u) << 16);
}
static __device__ __forceinline__ float ssp_f(float x) {
    const float t = __builtin_amdgcn_exp2f(x * 1.44269504f);
    return 0.69314718f * (__builtin_amdgcn_logf(1.f + t) - 1.f);
}

// ---------------------------------------------------------------------------
// Transpose+convert the three 256x256 f32 weight matrices to bf16 B^T once.
// ---------------------------------------------------------------------------
__global__ void convt_kernel(const float* __restrict__ b0, const float* __restrict__ b1,
                             const float* __restrict__ b2, __bf16* __restrict__ t0,
                             __bf16* __restrict__ t1, __bf16* __restrict__ t2)
{
    const int i   = blockIdx.x * 256 + threadIdx.x;   // 0..196607
    const int mat = i >> 16;
    const int e   = i & 65535;
    const int k   = e >> 8;
    const int j   = e & 255;
    const float* src = (mat == 0) ? b0 : (mat == 1) ? b1 : b2;
    __bf16*      dst = (mat == 0) ? t0 : (mat == 1) ? t1 : t2;
    dst[j * 256 + k] = (__bf16)src[k * 256 + j];
}

// ---------------------------------------------------------------------------
// x = bf16(h @ lin1_w): LDS-free, B-frags direct from L2 (R17, unchanged).
// Block = 64 rows x 256 cols; wave owns 64 cols (acc[4][4]). No barriers.
// ---------------------------------------------------------------------------
__global__ __launch_bounds__(256, 2)
void node_gemm0(const float* __restrict__ A, const __bf16* __restrict__ Bt,
                unsigned short* __restrict__ outb, int M)
{
    const int tid  = threadIdx.x;
    const int wave = tid >> 6;
    const int l    = tid & 63;
    const int lrow = l & 15;
    const int kg   = (l >> 4) << 3;
    const int row0 = blockIdx.x << 6;
    const int jw   = wave << 6;

    f32x4 acc[4][4];
    const f32x4 z4 = {0.f, 0.f, 0.f, 0.f};
    #pragma unroll
    for (int m = 0; m < 4; ++m)
        #pragma unroll
        for (int n = 0; n < 4; ++n) acc[m][n] = z4;

    #pragma unroll
    for (int ks = 0; ks < 8; ++ks) {
        const int k0 = (ks << 5) + kg;
        bf16x8 bfr[4];
        #pragma unroll
        for (int n = 0; n < 4; ++n)
            bfr[n] = *(const bf16x8*)(Bt + (jw + (n << 4) + lrow) * 256 + k0);
        #pragma unroll
        for (int m = 0; m < 4; ++m) {
            const int row = row0 + (m << 4) + lrow;
            bf16x8 af;
            if (row < M) {
                const float* ap = A + row * 256 + k0;
                const f32x4 a0 = *(const f32x4*)(ap);
                const f32x4 a1 = *(const f32x4*)(ap + 4);
                #pragma unroll
                for (int b = 0; b < 4; ++b) { af[b] = (__bf16)a0[b]; af[b + 4] = (__bf16)a1[b]; }
            } else {
                #pragma unroll
                for (int b = 0; b < 8; ++b) af[b] = (__bf16)0.f;
            }
            #pragma unroll
            for (int n = 0; n < 4; ++n)
                acc[m][n] = __builtin_amdgcn_mfma_f32_16x16x32_bf16(af, bfr[n], acc[m][n], 0, 0, 0);
        }
    }

    #pragma unroll
    for (int m = 0; m < 4; ++m)
        #pragma unroll
        for (int n = 0; n < 4; ++n) {
            const int j = jw + (n << 4) + lrow;
            #pragma unroll
            for (int r = 0; r < 4; ++r) {
                const int row = row0 + (m << 4) + ((l >> 4) << 2) + r;
                if (row < M) outb[row * 256 + j] = bfbits(acc[m][n][r]);
            }
        }
}

// ---------------------------------------------------------------------------
// FUSED TAIL: out = ssp(agg @ lin2_w + b2) @ lin_w + b  — one kernel.
// Phase 1 -> x2 tile in LDS (64x256 bf16, swizzled, 32KB); Phase 2 from LDS.
// B-frags for both phases direct from L2 (bt1/bt2). 1 barrier.
// ---------------------------------------------------------------------------
__global__ __launch_bounds__(256, 2)
void fused_tail(const float* __restrict__ agg, const __bf16* __restrict__ Bt1,
                const float* __restrict__ bias1, const __bf16* __restrict__ Bt2,
                const float* __restrict__ bias2, float* __restrict__ out, int M)
{
    __shared__ char tb[32768];
    const int tid  = threadIdx.x;
    const int wave = tid >> 6;
    const int l    = tid & 63;
    const int lrow = l & 15;
    const int g    = l >> 4;
    const int kg   = g << 3;
    const int row0 = blockIdx.x << 6;
    const int jw   = wave << 6;

    const f32x4 z4 = {0.f, 0.f, 0.f, 0.f};

    // ---- phase 1: acc1 = agg @ Bt1 ----
    f32x4 acc[4][4];
    #pragma unroll
    for (int m = 0; m < 4; ++m)
        #pragma unroll
        for (int n = 0; n < 4; ++n) acc[m][n] = z4;

    #pragma unroll
    for (int ks = 0; ks < 8; ++ks) {
        const int k0 = (ks << 5) + kg;
        bf16x8 bfr[4];
        #pragma unroll
        for (int n = 0; n < 4; ++n)
            bfr[n] = *(const bf16x8*)(Bt1 + (jw + (n << 4) + lrow) * 256 + k0);
        #pragma unroll
        for (int m = 0; m < 4; ++m) {
            const int row = row0 + (m << 4) + lrow;
            bf16x8 af;
            if (row < M) {
                const float* ap = agg + row * 256 + k0;
                const f32x4 a0 = *(const f32x4*)(ap);
                const f32x4 a1 = *(const f32x4*)(ap + 4);
                #pragma unroll
                for (int b = 0; b < 4; ++b) { af[b] = (__bf16)a0[b]; af[b + 4] = (__bf16)a1[b]; }
            } else {
                #pragma unroll
                for (int b = 0; b < 8; ++b) af[b] = (__bf16)0.f;
            }
            #pragma unroll
            for (int n = 0; n < 4; ++n)
                acc[m][n] = __builtin_amdgcn_mfma_f32_16x16x32_bf16(af, bfr[n], acc[m][n], 0, 0, 0);
        }
    }

    // ssp epilogue -> x2 tile in LDS (swizzled by row&7)
    #pragma unroll
    for (int m = 0; m < 4; ++m)
        #pragma unroll
        for (int n = 0; n < 4; ++n) {
            const int j = jw + (n << 4) + lrow;
            const float bv = bias1[j];
            #pragma unroll
            for (int r = 0; r < 4; ++r) {
                const int e = (m << 4) + (g << 2) + r;      // local row
                const float v = ssp_f(acc[m][n][r] + bv);
                *(__bf16*)(tb + ((e * 512 + j * 2) ^ ((e & 7) << 4))) = (__bf16)v;
            }
        }
    __syncthreads();

    // ---- phase 2: out = x2 @ Bt2 + bias2 ----
    #pragma unroll
    for (int m = 0; m < 4; ++m)
        #pragma unroll
        for (int n = 0; n < 4; ++n) acc[m][n] = z4;

    #pragma unroll
    for (int ks = 0; ks < 8; ++ks) {
        const int k0 = (ks << 5) + kg;
        bf16x8 bfr[4];
        #pragma unroll
        for (int n = 0; n < 4; ++n)
            bfr[n] = *(const bf16x8*)(Bt2 + (jw + (n << 4) + lrow) * 256 + k0);
        #pragma unroll
        for (int m = 0; m < 4; ++m) {
            const int e = (m << 4) + lrow;
            const bf16x8 af = *(const bf16x8*)(tb + ((e * 512 + k0 * 2) ^ ((e & 7) << 4)));
            #pragma unroll
            for (int n = 0; n < 4; ++n)
                acc[m][n] = __builtin_amdgcn_mfma_f32_16x16x32_bf16(af, bfr[n], acc[m][n], 0, 0, 0);
        }
    }

    #pragma unroll
    for (int m = 0; m < 4; ++m)
        #pragma unroll
        for (int n = 0; n < 4; ++n) {
            const int j = jw + (n << 4) + lrow;
            const float bv = bias2[j];
            #pragma unroll
            for (int r = 0; r < 4; ++r) {
                const int row = row0 + (m << 4) + ((l >> 4) << 2) + r;
                if (row < M) out[row * 256 + j] = acc[m][n][r] + bv;
            }
        }
}

// ---------------------------------------------------------------------------
// Counting sort + meta precompute + fused pos copy (unchanged)
// ---------------------------------------------------------------------------
__global__ void hist_kernel(const int* __restrict__ ei, int* __restrict__ hist)
{
    const int i = blockIdx.x * 256 + threadIdx.x;
    if (i < N_EDGES) atomicAdd(&hist[ei[N_EDGES + i]], 1);
}

__global__ void scan_kernel(int* __restrict__ hist)
{
    __shared__ int part[1024];
    const int t  = threadIdx.x;
    const int CH = (N_NODES + 1023) / 1024;   // 25
    const int lo = t * CH;
    const int hi = (lo + CH < N_NODES) ? lo + CH : N_NODES;
    int s = 0;
    for (int i = lo; i < hi; ++i) s += hist[i];
    part[t] = s;
    __syncthreads();
    for (int off = 1; off < 1024; off <<= 1) {
        const int v = part[t];
        const int u = (t >= off) ? part[t - off] : 0;
        __syncthreads();
        part[t] = v + u;
        __syncthreads();
    }
    int base = (t == 0) ? 0 : part[t - 1];
    for (int i = lo; i < hi; ++i) { const int v = hist[i]; hist[i] = base; base += v; }
}

__global__ void scatter_meta(const int* __restrict__ ei, const float* __restrict__ pos,
                             int* __restrict__ hist, float4* __restrict__ meta,
                             float* __restrict__ out_pos)
{
    const int i = blockIdx.x * 256 + threadIdx.x;
    if (i >= N_EDGES) return;
    if (i < N_NODES * 3) out_pos[i] = pos[i];
    const int r = ei[i];
    const int c = ei[N_EDGES + i];
    const float dx = pos[r * 3 + 0] - pos[c * 3 + 0];
    const float dy = pos[r * 3 + 1] - pos[c * 3 + 1];
    const float dz = pos[r * 3 + 2] - pos[c * 3 + 2];
    const float d  = __fsqrt_rn(dx * dx + dy * dy + dz * dz);
    const float C  = 0.5f * (__cosf(d * 0.31415926535f) + 1.f);
    const int p = atomicAdd(&hist[c], 1);
    float4 m;
    m.x = d; m.y = C;
    m.z = __int_as_float(r); m.w = __int_as_float(c);
    meta[p] = m;
}

// ---------------------------------------------------------------------------
// Fused edge kernel — byte-identical to R16/R17 (measured 269us, best).
// ---------------------------------------------------------------------------
__global__ __launch_bounds__(256, 2)
void edge_kernel(const float4* __restrict__ meta,
                 const float* __restrict__ w1, const float* __restrict__ b1,
                 const float* __restrict__ w2, const float* __restrict__ b2,
                 const unsigned short* __restrict__ xb, float* __restrict__ agg)
{
    extern __shared__ char lds[];
    char* w2t = lds;
    char* rb  = lds + 65536;          // tb = rb[0:16K]; ms = rb[0:8K]
    char* gsp = rb + 12288;           // gs = rb[12K:16K] (disjoint from ms+colsm)
    int* colsm = (int*)(rb + 8192);

    const int tid   = threadIdx.x;
    const int wave  = tid >> 6;
    const int l     = tid & 63;
    const int lrow  = l & 15;
    const int g     = l >> 4;
    const int kg    = g << 3;
    const int half  = blockIdx.x & 1;
    const int jblk  = half << 7;
    const int group = blockIdx.x >> 1;

    // stage W2^T half
    {
        const int j   = tid & 127;
        const int k2b = (tid >> 7) << 6;
        for (int i = 0; i < 64; ++i) {
            const int k = (k2b + i) * 2;
            const float v0 = w2[k * 256 + jblk + j];
            const float v1 = w2[(k + 1) * 256 + jblk + j];
            const unsigned pack = (unsigned)bfbits(v0) | ((unsigned)bfbits(v1) << 16);
            *(unsigned*)(w2t + ((j * 512 + k * 2) ^ ((j & 7) << 4))) = pack;
        }
    }

    // W1 B-fragments in registers (wave owns 64 filter cols)
    const float dlt    = 10.f / 49.f;
    const float coeff2 = (-0.5f / (dlt * dlt)) * 1.44269504f;   // log2e folded
    bf16x8 w1f[4][2];
    #pragma unroll
    for (int n = 0; n < 4; ++n)
        #pragma unroll
        for (int ks = 0; ks < 2; ++ks) {
            bf16x8 v;
            #pragma unroll
            for (int b = 0; b < 8; ++b) {
                const int k = (ks << 5) + kg + b;
                const int j = (wave << 6) + (n << 4) + lrow;
                v[b] = (k < 50) ? (__bf16)w1[k * 256 + j] : (__bf16)0.f;
            }
            w1f[n][ks] = v;
        }
    float b1v[4], b2v[2];
    #pragma unroll
    for (int n = 0; n < 4; ++n) b1v[n] = b1[(wave << 6) + (n << 4) + lrow];
    #pragma unroll
    for (int n = 0; n < 2; ++n) b2v[n] = b2[jblk + (wave << 5) + (n << 4) + lrow];

    BAR();   // w2t ready

    const f32x4 z4 = {0.f, 0.f, 0.f, 0.f};
    const int CH = (NTILES + 255) / 256;    // 49 tiles per group, contiguous
    const int t0 = group * CH;
    int t1 = t0 + CH; if (t1 > NTILES) t1 = NTILES;

    const int ge  = tid >> 3;         // gaussian producer: edge 0..31
    const int gkb = (tid & 7) << 3;   // gaussian producer: k-base

    // reader run-carry state (used by tid < 128 only)
    int   rprev  = -1;
    float rs     = 0.f;
    int   rfirst = 1;
    float* aj    = agg + jblk + (tid & 127);

    // meta prefetch
    float4 mv = meta[(t0 << 5) + (l & 31)];

    for (int t = t0; t < t1; ++t) {
        const float d  = mv.x;
        const float Cc = mv.y;
        const int   r  = __float_as_int(mv.z);
        const int   c  = __float_as_int(mv.w);
        if (t + 1 < t1) mv = meta[((t + 1) << 5) + (l & 31)];

        // hoisted bf16 x-gather (in flight until msg epilogue)
        float xv[2][2][4];
        #pragma unroll
        for (int m = 0; m < 2; ++m)
            #pragma unroll
            for (int r4 = 0; r4 < 4; ++r4) {
                const int e  = (m << 4) + (g << 2) + r4;
                const int re = __shfl(r, e, 64);
                #pragma unroll
                for (int n = 0; n < 2; ++n) {
                    const int jloc = (wave << 5) + (n << 4) + lrow;
                    xv[m][n][r4] = bf2f(xb[re * 256 + jblk + jloc]);
                }
            }

        // gaussian producer: thread (ge, gkb) computes 8 k-values for edge ge
        const float gd = __shfl(d, ge, 64);
        bf16x8 gv;
        #pragma unroll
        for (int b = 0; b < 8; ++b) {
            const int k = gkb + b;
            float gval = 0.f;
            if (k < 50) {
                const float u = gd - (float)k * dlt;
                gval = __builtin_amdgcn_exp2f(coeff2 * u * u);
            }
            gv[b] = (__bf16)gval;
        }
        // gs disjoint from reader's ms+colsm -> no pre-write barrier needed
        *(bf16x8*)(gsp + ((ge * 128 + (gkb << 1)) ^ ((ge & 7) << 4))) = gv;
        BAR();   // B2: gaussians visible

        // ---- GEMM1: gauss[32][64] @ W1 -> acc1 (wave owns 64 filter cols)
        bf16x8 af[2][2];
        #pragma unroll
        for (int m = 0; m < 2; ++m) {
            const int e = (m << 4) + lrow;
            #pragma unroll
            for (int ks = 0; ks < 2; ++ks)
                af[m][ks] = *(const bf16x8*)(gsp + ((e * 128 + ((ks << 5) + kg) * 2) ^ ((e & 7) << 4)));
        }
        f32x4 acc1[2][4];
        #pragma unroll
        for (int m = 0; m < 2; ++m)
            #pragma unroll
            for (int n = 0; n < 4; ++n) acc1[m][n] = z4;
        #pragma unroll
        for (int ks = 0; ks < 2; ++ks)
            #pragma unroll
            for (int m = 0; m < 2; ++m)
                #pragma unroll
                for (int n = 0; n < 4; ++n)
                    acc1[m][n] = __builtin_amdgcn_mfma_f32_16x16x32_bf16(af[m][ks], w1f[n][ks], acc1[m][n], 0, 0, 0);
        BAR();   // B3: gs reads done; tb region writable

        // ---- epilogue1: t = ssp(acc1 + b1) -> tb bf16 (swizzled)
        #pragma unroll
        for (int m = 0; m < 2; ++m)
            #pragma unroll
            for (int n = 0; n < 4; ++n)
                #pragma unroll
                for (int r4 = 0; r4 < 4; ++r4) {
                    const int e = (m << 4) + (g << 2) + r4;
                    const int k = (wave << 6) + (n << 4) + lrow;
                    const float v = ssp_f(acc1[m][n][r4] + b1v[n]);
                    *(__bf16*)(rb + ((e * 512 + k * 2) ^ ((e & 7) << 4))) = (__bf16)v;
                }
        BAR();   // B4: tb ready

        // ---- GEMM2: t[32][256] @ W2[:, jblk:+128] -> acc2
        f32x4 acc2[2][2];
        #pragma unroll
        for (int m = 0; m < 2; ++m) { acc2[m][0] = z4; acc2[m][1] = z4; }
        #pragma unroll
        for (int ks = 0; ks < 8; ++ks) {
            const int k0 = (ks << 5) + kg;
            bf16x8 bfr[2];
            #pragma unroll
            for (int n = 0; n < 2; ++n) {
                const int jl = (wave << 5) + (n << 4) + lrow;
                bfr[n] = *(const bf16x8*)(w2t + ((jl * 512 + k0 * 2) ^ ((jl & 7) << 4)));
            }
            #pragma unroll
            for (int m = 0; m < 2; ++m) {
                const int e = (m << 4) + lrow;
                const bf16x8 a = *(const bf16x8*)(rb + ((e * 512 + k0 * 2) ^ ((e & 7) << 4)));
                #pragma unroll
                for (int n = 0; n < 2; ++n)
                    acc2[m][n] = __builtin_amdgcn_mfma_f32_16x16x32_bf16(a, bfr[n], acc2[m][n], 0, 0, 0);
            }
        }
        BAR();   // B5: tb reads done; ms region writable

        // ---- msg epilogue: (acc2+b2)*C * xv -> ms[j][e] bf16 (swizzled)
        #pragma unroll
        for (int m = 0; m < 2; ++m) {
            const int base_e = (m << 4) + (g << 2);
            #pragma unroll
            for (int n = 0; n < 2; ++n) {
                const int jloc = (wave << 5) + (n << 4) + lrow;
                float vv[4];
                #pragma unroll
                for (int r4 = 0; r4 < 4; ++r4) {
                    const int e  = base_e + r4;
                    const float Ce = __shfl(Cc, e, 64);
                    vv[r4] = (acc2[m][n][r4] + b2v[n]) * Ce * xv[m][n][r4];
                }
                uint32x2 pk;
                pk[0] = (unsigned)bfbits(vv[0]) | ((unsigned)bfbits(vv[1]) << 16);
                pk[1] = (unsigned)bfbits(vv[2]) | ((unsigned)bfbits(vv[3]) << 16);
                *(uint32x2*)(rb + ((jloc * 64 + (base_e << 1)) ^ ((jloc & 7) << 4))) = pk;
            }
        }
        if (tid < 32) colsm[tid] = c;
        BAR();   // B6: ms + colsm ready

        // ---- reader: 128 threads, one j each, 32 edges; run-carry reduce
        if (tid < 128) {
            const int j = tid;
            const bf16x8 q0 = *(const bf16x8*)(rb + ((j * 64 +  0) ^ ((j & 7) << 4)));
            const bf16x8 q1 = *(const bf16x8*)(rb + ((j * 64 + 16) ^ ((j & 7) << 4)));
            const bf16x8 q2 = *(const bf16x8*)(rb + ((j * 64 + 32) ^ ((j & 7) << 4)));
            const bf16x8 q3 = *(const bf16x8*)(rb + ((j * 64 + 48) ^ ((j & 7) << 4)));
            #pragma unroll
            for (int e = 0; e < 32; ++e) {
                const float v = (float)(e < 8 ? q0[e] : e < 16 ? q1[e - 8] :
                                        e < 24 ? q2[e - 16] : q3[e - 24]);
                const int ce = colsm[e];
                if (ce != rprev) {                    // wave-uniform branch
                    if (rprev >= 0) {
                        if (rfirst) { atomicAdd(aj + rprev * 256, rs); rfirst = 0; }
                        else        { aj[rprev * 256] = rs; }
                    }
                    rs = 0.f; rprev = ce;
                }
                rs += v;
            }
        }
    }
    // final flush: run may continue into the next chunk -> atomic
    if (tid < 128 && rprev >= 0) atomicAdd(aj + rprev * 256, rs);
}

extern "C" void kernel_launch(void* const* d_in, const int* in_sizes, int n_in,
                              void* d_out, int out_size, void* d_ws, size_t ws_size,
                              hipStream_t stream)
{
    const float* h      = (const float*)d_in[0];
    const float* pos    = (const float*)d_in[1];
    const float* lin1_w = (const float*)d_in[2];
    const float* lin2_w = (const float*)d_in[3];
    const float* lin2_b = (const float*)d_in[4];
    const float* mlp_w1 = (const float*)d_in[5];
    const float* mlp_b1 = (const float*)d_in[6];
    const float* mlp_w2 = (const float*)d_in[7];
    const float* mlp_b2 = (const float*)d_in[8];
    const float* lin_w  = (const float*)d_in[9];
    const float* lin_b  = (const float*)d_in[10];
    const int*   ei     = (const int*)d_in[11];
    float* out = (float*)d_out;

    // ws layout: xb bf16 12.8M | agg 25.6M | meta 6.4M | hist 0.1M | Bt x3
    unsigned short* xb  = (unsigned short*)d_ws;
    float*  agg  = (float*)((char*)d_ws + 12800000);
    float4* meta = (float4*)((char*)d_ws + 38400000);
    int*    hist = (int*)((char*)d_ws + 44800000);
    __bf16* bt0  = (__bf16*)((char*)d_ws + 44900000);   // 131072 B each
    __bf16* bt1  = bt0 + 65536;
    __bf16* bt2  = bt1 + 65536;

    (void)hipFuncSetAttribute((const void*)edge_kernel,
                              hipFuncAttributeMaxDynamicSharedMemorySize, 81920);

    (void)hipMemsetAsync(agg, 0, (size_t)N_NODES * 256 * sizeof(float), stream);
    (void)hipMemsetAsync(hist, 0, (size_t)N_NODES * sizeof(int), stream);

    const dim3 blk(256);
    const int mt = (N_NODES + 63) / 64;     // 391 row-tiles
    const int eb = (N_EDGES + 255) / 256;   // 1563 blocks

    // one-shot B^T bf16 conversion for the three node GEMMs
    convt_kernel<<<dim3(768), blk, 0, stream>>>(lin1_w, lin2_w, lin_w, bt0, bt1, bt2);

    // x = bf16(h @ lin1_w)
    node_gemm0<<<dim3(mt), blk, 0, stream>>>(h, bt0, xb, N_NODES);

    // counting sort by col + per-edge meta (d, C, r, c) + fused pos copy
    hist_kernel<<<dim3(eb), blk, 0, stream>>>(ei, hist);
    scan_kernel<<<dim3(1), dim3(1024), 0, stream>>>(hist);
    scatter_meta<<<dim3(eb), blk, 0, stream>>>(ei, pos, hist, meta, out + N_NODES * 256);

    // fused edge pipeline -> agg
    edge_kernel<<<dim3(512), blk, 81920, stream>>>(meta, mlp_w1, mlp_b1,
                                                   mlp_w2, mlp_b2, xb, agg);

    // out = ssp(agg @ lin2_w + lin2_b) @ lin_w + lin_b  (fused, one kernel)
    fused_tail<<<dim3(mt), blk, 0, stream>>>(agg, bt1, lin2_b, bt2, lin_b, out, N_NODES);
}

// Round 19
// 398.244 us; speedup vs baseline: 1.6456x; 1.0197x over previous
//
#include <hip/hip_runtime.h>
#include <hip/hip_bf16.h>

#define N_NODES 25000
#define N_EDGES 400000
#define NTILES (N_EDGES / 32)   // 12500 exact

typedef __attribute__((ext_vector_type(8))) __bf16 bf16x8;
typedef __attribute__((ext_vector_type(4))) float f32x4;
typedef __attribute__((ext_vector_type(2))) unsigned uint32x2;

// Raw workgroup barrier that does NOT drain vmcnt: waits only LDS ops.
#define BAR() do {                                          \
    asm volatile("s_waitcnt lgkmcnt(0)" ::: "memory");      \
    __builtin_amdgcn_s_barrier();                           \
    asm volatile("" ::: "memory");                          \
} while (0)

static __device__ __forceinline__ unsigned short bfbits(float f) {
    __bf16 h = (__bf16)f;
    return __builtin_bit_cast(unsigned short, h);
}
static __device__ __forceinline__ float bf2f(unsigned short u) {
    return __builtin_bit_cast(float, ((unsigned)u) << 16);
}
static __device__ __forceinline__ float ssp_f(float x) {
    const float t = __builtin_amdgcn_exp2f(x * 1.44269504f);
    return 0.69314718f * (__builtin_amdgcn_logf(1.f + t) - 1.f);
}

// ---------------------------------------------------------------------------
// Transpose+convert the three 256x256 weights to bf16 B^T; also zero hist
// (runs before hist_kernel in stream order).
// ---------------------------------------------------------------------------
__global__ void convt_kernel(const float* __restrict__ b0, const float* __restrict__ b1,
                             const float* __restrict__ b2, __bf16* __restrict__ t0,
                             __bf16* __restrict__ t1, __bf16* __restrict__ t2,
                             int* __restrict__ hist)
{
    const int i   = blockIdx.x * 256 + threadIdx.x;   // 0..196607
    if (i < N_NODES) hist[i] = 0;
    const int mat = i >> 16;
    const int e   = i & 65535;
    const int k   = e >> 8;
    const int j   = e & 255;
    const float* src = (mat == 0) ? b0 : (mat == 1) ? b1 : b2;
    __bf16*      dst = (mat == 0) ? t0 : (mat == 1) ? t1 : t2;
    dst[j * 256 + k] = (__bf16)src[k * 256 + j];
}

// ---------------------------------------------------------------------------
// x = bf16(h @ lin1_w): LDS-free, B-frags direct from L2 (R17, unchanged).
// ---------------------------------------------------------------------------
__global__ __launch_bounds__(256, 2)
void node_gemm0(const float* __restrict__ A, const __bf16* __restrict__ Bt,
                unsigned short* __restrict__ outb, int M)
{
    const int tid  = threadIdx.x;
    const int wave = tid >> 6;
    const int l    = tid & 63;
    const int lrow = l & 15;
    const int kg   = (l >> 4) << 3;
    const int row0 = blockIdx.x << 6;
    const int jw   = wave << 6;

    f32x4 acc[4][4];
    const f32x4 z4 = {0.f, 0.f, 0.f, 0.f};
    #pragma unroll
    for (int m = 0; m < 4; ++m)
        #pragma unroll
        for (int n = 0; n < 4; ++n) acc[m][n] = z4;

    #pragma unroll
    for (int ks = 0; ks < 8; ++ks) {
        const int k0 = (ks << 5) + kg;
        bf16x8 bfr[4];
        #pragma unroll
        for (int n = 0; n < 4; ++n)
            bfr[n] = *(const bf16x8*)(Bt + (jw + (n << 4) + lrow) * 256 + k0);
        #pragma unroll
        for (int m = 0; m < 4; ++m) {
            const int row = row0 + (m << 4) + lrow;
            bf16x8 af;
            if (row < M) {
                const float* ap = A + row * 256 + k0;
                const f32x4 a0 = *(const f32x4*)(ap);
                const f32x4 a1 = *(const f32x4*)(ap + 4);
                #pragma unroll
                for (int b = 0; b < 4; ++b) { af[b] = (__bf16)a0[b]; af[b + 4] = (__bf16)a1[b]; }
            } else {
                #pragma unroll
                for (int b = 0; b < 8; ++b) af[b] = (__bf16)0.f;
            }
            #pragma unroll
            for (int n = 0; n < 4; ++n)
                acc[m][n] = __builtin_amdgcn_mfma_f32_16x16x32_bf16(af, bfr[n], acc[m][n], 0, 0, 0);
        }
    }

    #pragma unroll
    for (int m = 0; m < 4; ++m)
        #pragma unroll
        for (int n = 0; n < 4; ++n) {
            const int j = jw + (n << 4) + lrow;
            #pragma unroll
            for (int r = 0; r < 4; ++r) {
                const int row = row0 + (m << 4) + ((l >> 4) << 2) + r;
                if (row < M) outb[row * 256 + j] = bfbits(acc[m][n][r]);
            }
        }
}

// ---------------------------------------------------------------------------
// FUSED TAIL: out = ssp(agg @ lin2_w + b2) @ lin_w + b  (R18, unchanged).
// ---------------------------------------------------------------------------
__global__ __launch_bounds__(256, 2)
void fused_tail(const float* __restrict__ agg, const __bf16* __restrict__ Bt1,
                const float* __restrict__ bias1, const __bf16* __restrict__ Bt2,
                const float* __restrict__ bias2, float* __restrict__ out, int M)
{
    __shared__ char tb[32768];
    const int tid  = threadIdx.x;
    const int wave = tid >> 6;
    const int l    = tid & 63;
    const int lrow = l & 15;
    const int g    = l >> 4;
    const int kg   = g << 3;
    const int row0 = blockIdx.x << 6;
    const int jw   = wave << 6;

    const f32x4 z4 = {0.f, 0.f, 0.f, 0.f};

    f32x4 acc[4][4];
    #pragma unroll
    for (int m = 0; m < 4; ++m)
        #pragma unroll
        for (int n = 0; n < 4; ++n) acc[m][n] = z4;

    #pragma unroll
    for (int ks = 0; ks < 8; ++ks) {
        const int k0 = (ks << 5) + kg;
        bf16x8 bfr[4];
        #pragma unroll
        for (int n = 0; n < 4; ++n)
            bfr[n] = *(const bf16x8*)(Bt1 + (jw + (n << 4) + lrow) * 256 + k0);
        #pragma unroll
        for (int m = 0; m < 4; ++m) {
            const int row = row0 + (m << 4) + lrow;
            bf16x8 af;
            if (row < M) {
                const float* ap = agg + row * 256 + k0;
                const f32x4 a0 = *(const f32x4*)(ap);
                const f32x4 a1 = *(const f32x4*)(ap + 4);
                #pragma unroll
                for (int b = 0; b < 4; ++b) { af[b] = (__bf16)a0[b]; af[b + 4] = (__bf16)a1[b]; }
            } else {
                #pragma unroll
                for (int b = 0; b < 8; ++b) af[b] = (__bf16)0.f;
            }
            #pragma unroll
            for (int n = 0; n < 4; ++n)
                acc[m][n] = __builtin_amdgcn_mfma_f32_16x16x32_bf16(af, bfr[n], acc[m][n], 0, 0, 0);
        }
    }

    #pragma unroll
    for (int m = 0; m < 4; ++m)
        #pragma unroll
        for (int n = 0; n < 4; ++n) {
            const int j = jw + (n << 4) + lrow;
            const float bv = bias1[j];
            #pragma unroll
            for (int r = 0; r < 4; ++r) {
                const int e = (m << 4) + (g << 2) + r;
                const float v = ssp_f(acc[m][n][r] + bv);
                *(__bf16*)(tb + ((e * 512 + j * 2) ^ ((e & 7) << 4))) = (__bf16)v;
            }
        }
    __syncthreads();

    #pragma unroll
    for (int m = 0; m < 4; ++m)
        #pragma unroll
        for (int n = 0; n < 4; ++n) acc[m][n] = z4;

    #pragma unroll
    for (int ks = 0; ks < 8; ++ks) {
        const int k0 = (ks << 5) + kg;
        bf16x8 bfr[4];
        #pragma unroll
        for (int n = 0; n < 4; ++n)
            bfr[n] = *(const bf16x8*)(Bt2 + (jw + (n << 4) + lrow) * 256 + k0);
        #pragma unroll
        for (int m = 0; m < 4; ++m) {
            const int e = (m << 4) + lrow;
            const bf16x8 af = *(const bf16x8*)(tb + ((e * 512 + k0 * 2) ^ ((e & 7) << 4)));
            #pragma unroll
            for (int n = 0; n < 4; ++n)
                acc[m][n] = __builtin_amdgcn_mfma_f32_16x16x32_bf16(af, bfr[n], acc[m][n], 0, 0, 0);
        }
    }

    #pragma unroll
    for (int m = 0; m < 4; ++m)
        #pragma unroll
        for (int n = 0; n < 4; ++n) {
            const int j = jw + (n << 4) + lrow;
            const float bv = bias2[j];
            #pragma unroll
            for (int r = 0; r < 4; ++r) {
                const int row = row0 + (m << 4) + ((l >> 4) << 2) + r;
                if (row < M) out[row * 256 + j] = acc[m][n][r] + bv;
            }
        }
}

// ---------------------------------------------------------------------------
// hist + fused agg-zero (agg untouched until edge_kernel, 2 dispatches later)
// ---------------------------------------------------------------------------
__global__ void hist_kernel(const int* __restrict__ ei, int* __restrict__ hist,
                            float4* __restrict__ agg4)
{
    const int i = blockIdx.x * 256 + threadIdx.x;   // 400,128 threads
    const float4 z = {0.f, 0.f, 0.f, 0.f};
    for (int k = i; k < 1600000; k += 400128) agg4[k] = z;   // 25.6MB clear
    if (i < N_EDGES) atomicAdd(&hist[ei[N_EDGES + i]], 1);
}

__global__ void scan_kernel(int* __restrict__ hist)
{
    __shared__ int part[1024];
    const int t  = threadIdx.x;
    const int CH = (N_NODES + 1023) / 1024;   // 25
    const int lo = t * CH;
    const int hi = (lo + CH < N_NODES) ? lo + CH : N_NODES;
    int s = 0;
    for (int i = lo; i < hi; ++i) s += hist[i];
    part[t] = s;
    __syncthreads();
    for (int off = 1; off < 1024; off <<= 1) {
        const int v = part[t];
        const int u = (t >= off) ? part[t - off] : 0;
        __syncthreads();
        part[t] = v + u;
        __syncthreads();
    }
    int base = (t == 0) ? 0 : part[t - 1];
    for (int i = lo; i < hi; ++i) { const int v = hist[i]; hist[i] = base; base += v; }
}

__global__ void scatter_meta(const int* __restrict__ ei, const float* __restrict__ pos,
                             int* __restrict__ hist, float4* __restrict__ meta,
                             float* __restrict__ out_pos)
{
    const int i = blockIdx.x * 256 + threadIdx.x;
    if (i >= N_EDGES) return;
    if (i < N_NODES * 3) out_pos[i] = pos[i];
    const int r = ei[i];
    const int c = ei[N_EDGES + i];
    const float dx = pos[r * 3 + 0] - pos[c * 3 + 0];
    const float dy = pos[r * 3 + 1] - pos[c * 3 + 1];
    const float dz = pos[r * 3 + 2] - pos[c * 3 + 2];
    const float d  = __fsqrt_rn(dx * dx + dy * dy + dz * dz);
    const float C  = 0.5f * (__cosf(d * 0.31415926535f) + 1.f);
    const int p = atomicAdd(&hist[c], 1);
    float4 m;
    m.x = d; m.y = C;
    m.z = __int_as_float(r); m.w = __int_as_float(c);
    meta[p] = m;
}

// ---------------------------------------------------------------------------
// Fused edge kernel — byte-identical to R16/R17/R18 (measured 269-270us).
// ---------------------------------------------------------------------------
__global__ __launch_bounds__(256, 2)
void edge_kernel(const float4* __restrict__ meta,
                 const float* __restrict__ w1, const float* __restrict__ b1,
                 const float* __restrict__ w2, const float* __restrict__ b2,
                 const unsigned short* __restrict__ xb, float* __restrict__ agg)
{
    extern __shared__ char lds[];
    char* w2t = lds;
    char* rb  = lds + 65536;          // tb = rb[0:16K]; ms = rb[0:8K]
    char* gsp = rb + 12288;           // gs = rb[12K:16K] (disjoint from ms+colsm)
    int* colsm = (int*)(rb + 8192);

    const int tid   = threadIdx.x;
    const int wave  = tid >> 6;
    const int l     = tid & 63;
    const int lrow  = l & 15;
    const int g     = l >> 4;
    const int kg    = g << 3;
    const int half  = blockIdx.x & 1;
    const int jblk  = half << 7;
    const int group = blockIdx.x >> 1;

    // stage W2^T half
    {
        const int j   = tid & 127;
        const int k2b = (tid >> 7) << 6;
        for (int i = 0; i < 64; ++i) {
            const int k = (k2b + i) * 2;
            const float v0 = w2[k * 256 + jblk + j];
            const float v1 = w2[(k + 1) * 256 + jblk + j];
            const unsigned pack = (unsigned)bfbits(v0) | ((unsigned)bfbits(v1) << 16);
            *(unsigned*)(w2t + ((j * 512 + k * 2) ^ ((j & 7) << 4))) = pack;
        }
    }

    // W1 B-fragments in registers (wave owns 64 filter cols)
    const float dlt    = 10.f / 49.f;
    const float coeff2 = (-0.5f / (dlt * dlt)) * 1.44269504f;   // log2e folded
    bf16x8 w1f[4][2];
    #pragma unroll
    for (int n = 0; n < 4; ++n)
        #pragma unroll
        for (int ks = 0; ks < 2; ++ks) {
            bf16x8 v;
            #pragma unroll
            for (int b = 0; b < 8; ++b) {
                const int k = (ks << 5) + kg + b;
                const int j = (wave << 6) + (n << 4) + lrow;
                v[b] = (k < 50) ? (__bf16)w1[k * 256 + j] : (__bf16)0.f;
            }
            w1f[n][ks] = v;
        }
    float b1v[4], b2v[2];
    #pragma unroll
    for (int n = 0; n < 4; ++n) b1v[n] = b1[(wave << 6) + (n << 4) + lrow];
    #pragma unroll
    for (int n = 0; n < 2; ++n) b2v[n] = b2[jblk + (wave << 5) + (n << 4) + lrow];

    BAR();   // w2t ready

    const f32x4 z4 = {0.f, 0.f, 0.f, 0.f};
    const int CH = (NTILES + 255) / 256;    // 49 tiles per group, contiguous
    const int t0 = group * CH;
    int t1 = t0 + CH; if (t1 > NTILES) t1 = NTILES;

    const int ge  = tid >> 3;         // gaussian producer: edge 0..31
    const int gkb = (tid & 7) << 3;   // gaussian producer: k-base

    // reader run-carry state (used by tid < 128 only)
    int   rprev  = -1;
    float rs     = 0.f;
    int   rfirst = 1;
    float* aj    = agg + jblk + (tid & 127);

    // meta prefetch
    float4 mv = meta[(t0 << 5) + (l & 31)];

    for (int t = t0; t < t1; ++t) {
        const float d  = mv.x;
        const float Cc = mv.y;
        const int   r  = __float_as_int(mv.z);
        const int   c  = __float_as_int(mv.w);
        if (t + 1 < t1) mv = meta[((t + 1) << 5) + (l & 31)];

        // hoisted bf16 x-gather (in flight until msg epilogue)
        float xv[2][2][4];
        #pragma unroll
        for (int m = 0; m < 2; ++m)
            #pragma unroll
            for (int r4 = 0; r4 < 4; ++r4) {
                const int e  = (m << 4) + (g << 2) + r4;
                const int re = __shfl(r, e, 64);
                #pragma unroll
                for (int n = 0; n < 2; ++n) {
                    const int jloc = (wave << 5) + (n << 4) + lrow;
                    xv[m][n][r4] = bf2f(xb[re * 256 + jblk + jloc]);
                }
            }

        // gaussian producer: thread (ge, gkb) computes 8 k-values for edge ge
        const float gd = __shfl(d, ge, 64);
        bf16x8 gv;
        #pragma unroll
        for (int b = 0; b < 8; ++b) {
            const int k = gkb + b;
            float gval = 0.f;
            if (k < 50) {
                const float u = gd - (float)k * dlt;
                gval = __builtin_amdgcn_exp2f(coeff2 * u * u);
            }
            gv[b] = (__bf16)gval;
        }
        // gs disjoint from reader's ms+colsm -> no pre-write barrier needed
        *(bf16x8*)(gsp + ((ge * 128 + (gkb << 1)) ^ ((ge & 7) << 4))) = gv;
        BAR();   // B2: gaussians visible

        // ---- GEMM1: gauss[32][64] @ W1 -> acc1 (wave owns 64 filter cols)
        bf16x8 af[2][2];
        #pragma unroll
        for (int m = 0; m < 2; ++m) {
            const int e = (m << 4) + lrow;
            #pragma unroll
            for (int ks = 0; ks < 2; ++ks)
                af[m][ks] = *(const bf16x8*)(gsp + ((e * 128 + ((ks << 5) + kg) * 2) ^ ((e & 7) << 4)));
        }
        f32x4 acc1[2][4];
        #pragma unroll
        for (int m = 0; m < 2; ++m)
            #pragma unroll
            for (int n = 0; n < 4; ++n) acc1[m][n] = z4;
        #pragma unroll
        for (int ks = 0; ks < 2; ++ks)
            #pragma unroll
            for (int m = 0; m < 2; ++m)
                #pragma unroll
                for (int n = 0; n < 4; ++n)
                    acc1[m][n] = __builtin_amdgcn_mfma_f32_16x16x32_bf16(af[m][ks], w1f[n][ks], acc1[m][n], 0, 0, 0);
        BAR();   // B3: gs reads done; tb region writable

        // ---- epilogue1: t = ssp(acc1 + b1) -> tb bf16 (swizzled)
        #pragma unroll
        for (int m = 0; m < 2; ++m)
            #pragma unroll
            for (int n = 0; n < 4; ++n)
                #pragma unroll
                for (int r4 = 0; r4 < 4; ++r4) {
                    const int e = (m << 4) + (g << 2) + r4;
                    const int k = (wave << 6) + (n << 4) + lrow;
                    const float v = ssp_f(acc1[m][n][r4] + b1v[n]);
                    *(__bf16*)(rb + ((e * 512 + k * 2) ^ ((e & 7) << 4))) = (__bf16)v;
                }
        BAR();   // B4: tb ready

        // ---- GEMM2: t[32][256] @ W2[:, jblk:+128] -> acc2
        f32x4 acc2[2][2];
        #pragma unroll
        for (int m = 0; m < 2; ++m) { acc2[m][0] = z4; acc2[m][1] = z4; }
        #pragma unroll
        for (int ks = 0; ks < 8; ++ks) {
            const int k0 = (ks << 5) + kg;
            bf16x8 bfr[2];
            #pragma unroll
            for (int n = 0; n < 2; ++n) {
                const int jl = (wave << 5) + (n << 4) + lrow;
                bfr[n] = *(const bf16x8*)(w2t + ((jl * 512 + k0 * 2) ^ ((jl & 7) << 4)));
            }
            #pragma unroll
            for (int m = 0; m < 2; ++m) {
                const int e = (m << 4) + lrow;
                const bf16x8 a = *(const bf16x8*)(rb + ((e * 512 + k0 * 2) ^ ((e & 7) << 4)));
                #pragma unroll
                for (int n = 0; n < 2; ++n)
                    acc2[m][n] = __builtin_amdgcn_mfma_f32_16x16x32_bf16(a, bfr[n], acc2[m][n], 0, 0, 0);
            }
        }
        BAR();   // B5: tb reads done; ms region writable

        // ---- msg epilogue: (acc2+b2)*C * xv -> ms[j][e] bf16 (swizzled)
        #pragma unroll
        for (int m = 0; m < 2; ++m) {
            const int base_e = (m << 4) + (g << 2);
            #pragma unroll
            for (int n = 0; n < 2; ++n) {
                const int jloc = (wave << 5) + (n << 4) + lrow;
                float vv[4];
                #pragma unroll
                for (int r4 = 0; r4 < 4; ++r4) {
                    const int e  = base_e + r4;
                    const float Ce = __shfl(Cc, e, 64);
                    vv[r4] = (acc2[m][n][r4] + b2v[n]) * Ce * xv[m][n][r4];
                }
                uint32x2 pk;
                pk[0] = (unsigned)bfbits(vv[0]) | ((unsigned)bfbits(vv[1]) << 16);
                pk[1] = (unsigned)bfbits(vv[2]) | ((unsigned)bfbits(vv[3]) << 16);
                *(uint32x2*)(rb + ((jloc * 64 + (base_e << 1)) ^ ((jloc & 7) << 4))) = pk;
            }
        }
        if (tid < 32) colsm[tid] = c;
        BAR();   // B6: ms + colsm ready

        // ---- reader: 128 threads, one j each, 32 edges; run-carry reduce
        if (tid < 128) {
            const int j = tid;
            const bf16x8 q0 = *(const bf16x8*)(rb + ((j * 64 +  0) ^ ((j & 7) << 4)));
            const bf16x8 q1 = *(const bf16x8*)(rb + ((j * 64 + 16) ^ ((j & 7) << 4)));
            const bf16x8 q2 = *(const bf16x8*)(rb + ((j * 64 + 32) ^ ((j & 7) << 4)));
            const bf16x8 q3 = *(const bf16x8*)(rb + ((j * 64 + 48) ^ ((j & 7) << 4)));
            #pragma unroll
            for (int e = 0; e < 32; ++e) {
                const float v = (float)(e < 8 ? q0[e] : e < 16 ? q1[e - 8] :
                                        e < 24 ? q2[e - 16] : q3[e - 24]);
                const int ce = colsm[e];
                if (ce != rprev) {                    // wave-uniform branch
                    if (rprev >= 0) {
                        if (rfirst) { atomicAdd(aj + rprev * 256, rs); rfirst = 0; }
                        else        { aj[rprev * 256] = rs; }
                    }
                    rs = 0.f; rprev = ce;
                }
                rs += v;
            }
        }
    }
    // final flush: run may continue into the next chunk -> atomic
    if (tid < 128 && rprev >= 0) atomicAdd(aj + rprev * 256, rs);
}

extern "C" void kernel_launch(void* const* d_in, const int* in_sizes, int n_in,
                              void* d_out, int out_size, void* d_ws, size_t ws_size,
                              hipStream_t stream)
{
    const float* h      = (const float*)d_in[0];
    const float* pos    = (const float*)d_in[1];
    const float* lin1_w = (const float*)d_in[2];
    const float* lin2_w = (const float*)d_in[3];
    const float* lin2_b = (const float*)d_in[4];
    const float* mlp_w1 = (const float*)d_in[5];
    const float* mlp_b1 = (const float*)d_in[6];
    const float* mlp_w2 = (const float*)d_in[7];
    const float* mlp_b2 = (const float*)d_in[8];
    const float* lin_w  = (const float*)d_in[9];
    const float* lin_b  = (const float*)d_in[10];
    const int*   ei     = (const int*)d_in[11];
    float* out = (float*)d_out;

    // ws layout: xb bf16 12.8M | agg 25.6M | meta 6.4M | hist 0.1M | Bt x3
    unsigned short* xb  = (unsigned short*)d_ws;
    float*  agg  = (float*)((char*)d_ws + 12800000);
    float4* meta = (float4*)((char*)d_ws + 38400000);
    int*    hist = (int*)((char*)d_ws + 44800000);
    __bf16* bt0  = (__bf16*)((char*)d_ws + 44900000);   // 131072 B each
    __bf16* bt1  = bt0 + 65536;
    __bf16* bt2  = bt1 + 65536;

    (void)hipFuncSetAttribute((const void*)edge_kernel,
                              hipFuncAttributeMaxDynamicSharedMemorySize, 81920);

    const dim3 blk(256);
    const int mt = (N_NODES + 63) / 64;     // 391 row-tiles
    const int eb = (N_EDGES + 255) / 256;   // 1563 blocks

    // B^T bf16 conversion + hist zero
    convt_kernel<<<dim3(768), blk, 0, stream>>>(lin1_w, lin2_w, lin_w, bt0, bt1, bt2, hist);

    // x = bf16(h @ lin1_w)
    node_gemm0<<<dim3(mt), blk, 0, stream>>>(h, bt0, xb, N_NODES);

    // counting sort by col (hist also zeroes agg) + meta + fused pos copy
    hist_kernel<<<dim3(eb), blk, 0, stream>>>(ei, hist, (float4*)agg);
    scan_kernel<<<dim3(1), dim3(1024), 0, stream>>>(hist);
    scatter_meta<<<dim3(eb), blk, 0, stream>>>(ei, pos, hist, meta, out + N_NODES * 256);

    // fused edge pipeline -> agg
    edge_kernel<<<dim3(512), blk, 81920, stream>>>(meta, mlp_w1, mlp_b1,
                                                   mlp_w2, mlp_b2, xb, agg);

    // out = ssp(agg @ lin2_w + lin2_b) @ lin_w + lin_b  (fused, one kernel)
    fused_tail<<<dim3(mt), blk, 0, stream>>>(agg, bt1, lin2_b, bt2, lin_b, out, N_NODES);
}

// Round 20
// 387.176 us; speedup vs baseline: 1.6926x; 1.0286x over previous
//
#include <hip/hip_runtime.h>
#include <hip/hip_bf16.h>

#define N_NODES 25000
#define N_EDGES 400000
#define NTILES (N_EDGES / 32)   // 12500 exact
#define MT 391                  // (N_NODES+63)/64 row-tiles
#define EB 1563                 // (N_EDGES+255)/256 blocks

typedef __attribute__((ext_vector_type(8))) __bf16 bf16x8;
typedef __attribute__((ext_vector_type(4))) float f32x4;
typedef __attribute__((ext_vector_type(2))) unsigned uint32x2;

// Raw workgroup barrier that does NOT drain vmcnt: waits only LDS ops.
#define BAR() do {                                          \
    asm volatile("s_waitcnt lgkmcnt(0)" ::: "memory");      \
    __builtin_amdgcn_s_barrier();                           \
    asm volatile("" ::: "memory");                          \
} while (0)

static __device__ __forceinline__ unsigned short bfbits(float f) {
    __bf16 h = (__bf16)f;
    return __builtin_bit_cast(unsigned short, h);
}
static __device__ __forceinline__ float bf2f(unsigned short u) {
    return __builtin_bit_cast(float, ((unsigned)u) << 16);
}
static __device__ __forceinline__ float ssp_f(float x) {
    const float t = __builtin_amdgcn_exp2f(x * 1.44269504f);
    return 0.69314718f * (__builtin_amdgcn_logf(1.f + t) - 1.f);
}

// ---------------------------------------------------------------------------
// Transpose+convert the three 256x256 weights to bf16 B^T; also zero hist.
// ---------------------------------------------------------------------------
__global__ void convt_kernel(const float* __restrict__ b0, const float* __restrict__ b1,
                             const float* __restrict__ b2, __bf16* __restrict__ t0,
                             __bf16* __restrict__ t1, __bf16* __restrict__ t2,
                             int* __restrict__ hist)
{
    const int i   = blockIdx.x * 256 + threadIdx.x;   // 0..196607
    if (i < N_NODES) hist[i] = 0;
    const int mat = i >> 16;
    const int e   = i & 65535;
    const int k   = e >> 8;
    const int j   = e & 255;
    const float* src = (mat == 0) ? b0 : (mat == 1) ? b1 : b2;
    __bf16*      dst = (mat == 0) ? t0 : (mat == 1) ? t1 : t2;
    dst[j * 256 + k] = (__bf16)src[k * 256 + j];
}

// ---------------------------------------------------------------------------
// COMBO: blocks [0,MT) -> x = bf16(h @ lin1_w) (LDS-free MFMA GEMM);
//        blocks [MT, MT+EB) -> hist atomics + agg zero (memory-bound).
// Independent work merged into one dispatch for overlap.
// ---------------------------------------------------------------------------
__global__ __launch_bounds__(256, 2)
void gemm0_hist(const float* __restrict__ A, const __bf16* __restrict__ Bt,
                unsigned short* __restrict__ outb, int M,
                const int* __restrict__ ei, int* __restrict__ hist,
                float4* __restrict__ agg4)
{
    const int tid = threadIdx.x;

    if (blockIdx.x >= MT) {
        const int i = (blockIdx.x - MT) * 256 + tid;    // 0..400127
        const float4 z = {0.f, 0.f, 0.f, 0.f};
        for (int k = i; k < 1600000; k += 400128) agg4[k] = z;   // 25.6MB clear
        if (i < N_EDGES) atomicAdd(&hist[ei[N_EDGES + i]], 1);
        return;
    }

    const int wave = tid >> 6;
    const int l    = tid & 63;
    const int lrow = l & 15;
    const int kg   = (l >> 4) << 3;
    const int row0 = blockIdx.x << 6;
    const int jw   = wave << 6;

    f32x4 acc[4][4];
    const f32x4 z4 = {0.f, 0.f, 0.f, 0.f};
    #pragma unroll
    for (int m = 0; m < 4; ++m)
        #pragma unroll
        for (int n = 0; n < 4; ++n) acc[m][n] = z4;

    #pragma unroll
    for (int ks = 0; ks < 8; ++ks) {
        const int k0 = (ks << 5) + kg;
        bf16x8 bfr[4];
        #pragma unroll
        for (int n = 0; n < 4; ++n)
            bfr[n] = *(const bf16x8*)(Bt + (jw + (n << 4) + lrow) * 256 + k0);
        #pragma unroll
        for (int m = 0; m < 4; ++m) {
            const int row = row0 + (m << 4) + lrow;
            bf16x8 af;
            if (row < M) {
                const float* ap = A + row * 256 + k0;
                const f32x4 a0 = *(const f32x4*)(ap);
                const f32x4 a1 = *(const f32x4*)(ap + 4);
                #pragma unroll
                for (int b = 0; b < 4; ++b) { af[b] = (__bf16)a0[b]; af[b + 4] = (__bf16)a1[b]; }
            } else {
                #pragma unroll
                for (int b = 0; b < 8; ++b) af[b] = (__bf16)0.f;
            }
            #pragma unroll
            for (int n = 0; n < 4; ++n)
                acc[m][n] = __builtin_amdgcn_mfma_f32_16x16x32_bf16(af, bfr[n], acc[m][n], 0, 0, 0);
        }
    }

    #pragma unroll
    for (int m = 0; m < 4; ++m)
        #pragma unroll
        for (int n = 0; n < 4; ++n) {
            const int j = jw + (n << 4) + lrow;
            #pragma unroll
            for (int r = 0; r < 4; ++r) {
                const int row = row0 + (m << 4) + ((l >> 4) << 2) + r;
                if (row < M) outb[row * 256 + j] = bfbits(acc[m][n][r]);
            }
        }
}

// ---------------------------------------------------------------------------
// FUSED TAIL: out = ssp(agg @ lin2_w + b2) @ lin_w + b  (R18, unchanged).
// ---------------------------------------------------------------------------
__global__ __launch_bounds__(256, 2)
void fused_tail(const float* __restrict__ agg, const __bf16* __restrict__ Bt1,
                const float* __restrict__ bias1, const __bf16* __restrict__ Bt2,
                const float* __restrict__ bias2, float* __restrict__ out, int M)
{
    __shared__ char tb[32768];
    const int tid  = threadIdx.x;
    const int wave = tid >> 6;
    const int l    = tid & 63;
    const int lrow = l & 15;
    const int g    = l >> 4;
    const int kg   = g << 3;
    const int row0 = blockIdx.x << 6;
    const int jw   = wave << 6;

    const f32x4 z4 = {0.f, 0.f, 0.f, 0.f};

    f32x4 acc[4][4];
    #pragma unroll
    for (int m = 0; m < 4; ++m)
        #pragma unroll
        for (int n = 0; n < 4; ++n) acc[m][n] = z4;

    #pragma unroll
    for (int ks = 0; ks < 8; ++ks) {
        const int k0 = (ks << 5) + kg;
        bf16x8 bfr[4];
        #pragma unroll
        for (int n = 0; n < 4; ++n)
            bfr[n] = *(const bf16x8*)(Bt1 + (jw + (n << 4) + lrow) * 256 + k0);
        #pragma unroll
        for (int m = 0; m < 4; ++m) {
            const int row = row0 + (m << 4) + lrow;
            bf16x8 af;
            if (row < M) {
                const float* ap = agg + row * 256 + k0;
                const f32x4 a0 = *(const f32x4*)(ap);
                const f32x4 a1 = *(const f32x4*)(ap + 4);
                #pragma unroll
                for (int b = 0; b < 4; ++b) { af[b] = (__bf16)a0[b]; af[b + 4] = (__bf16)a1[b]; }
            } else {
                #pragma unroll
                for (int b = 0; b < 8; ++b) af[b] = (__bf16)0.f;
            }
            #pragma unroll
            for (int n = 0; n < 4; ++n)
                acc[m][n] = __builtin_amdgcn_mfma_f32_16x16x32_bf16(af, bfr[n], acc[m][n], 0, 0, 0);
        }
    }

    #pragma unroll
    for (int m = 0; m < 4; ++m)
        #pragma unroll
        for (int n = 0; n < 4; ++n) {
            const int j = jw + (n << 4) + lrow;
            const float bv = bias1[j];
            #pragma unroll
            for (int r = 0; r < 4; ++r) {
                const int e = (m << 4) + (g << 2) + r;
                const float v = ssp_f(acc[m][n][r] + bv);
                *(__bf16*)(tb + ((e * 512 + j * 2) ^ ((e & 7) << 4))) = (__bf16)v;
            }
        }
    __syncthreads();

    #pragma unroll
    for (int m = 0; m < 4; ++m)
        #pragma unroll
        for (int n = 0; n < 4; ++n) acc[m][n] = z4;

    #pragma unroll
    for (int ks = 0; ks < 8; ++ks) {
        const int k0 = (ks << 5) + kg;
        bf16x8 bfr[4];
        #pragma unroll
        for (int n = 0; n < 4; ++n)
            bfr[n] = *(const bf16x8*)(Bt2 + (jw + (n << 4) + lrow) * 256 + k0);
        #pragma unroll
        for (int m = 0; m < 4; ++m) {
            const int e = (m << 4) + lrow;
            const bf16x8 af = *(const bf16x8*)(tb + ((e * 512 + k0 * 2) ^ ((e & 7) << 4)));
            #pragma unroll
            for (int n = 0; n < 4; ++n)
                acc[m][n] = __builtin_amdgcn_mfma_f32_16x16x32_bf16(af, bfr[n], acc[m][n], 0, 0, 0);
        }
    }

    #pragma unroll
    for (int m = 0; m < 4; ++m)
        #pragma unroll
        for (int n = 0; n < 4; ++n) {
            const int j = jw + (n << 4) + lrow;
            const float bv = bias2[j];
            #pragma unroll
            for (int r = 0; r < 4; ++r) {
                const int row = row0 + (m << 4) + ((l >> 4) << 2) + r;
                if (row < M) out[row * 256 + j] = acc[m][n][r] + bv;
            }
        }
}

__global__ void scan_kernel(int* __restrict__ hist)
{
    __shared__ int part[1024];
    const int t  = threadIdx.x;
    const int CH = (N_NODES + 1023) / 1024;   // 25
    const int lo = t * CH;
    const int hi = (lo + CH < N_NODES) ? lo + CH : N_NODES;
    int s = 0;
    for (int i = lo; i < hi; ++i) s += hist[i];
    part[t] = s;
    __syncthreads();
    for (int off = 1; off < 1024; off <<= 1) {
        const int v = part[t];
        const int u = (t >= off) ? part[t - off] : 0;
        __syncthreads();
        part[t] = v + u;
        __syncthreads();
    }
    int base = (t == 0) ? 0 : part[t - 1];
    for (int i = lo; i < hi; ++i) { const int v = hist[i]; hist[i] = base; base += v; }
}

__global__ void scatter_meta(const int* __restrict__ ei, const float* __restrict__ pos,
                             int* __restrict__ hist, float4* __restrict__ meta,
                             float* __restrict__ out_pos)
{
    const int i = blockIdx.x * 256 + threadIdx.x;
    if (i >= N_EDGES) return;
    if (i < N_NODES * 3) out_pos[i] = pos[i];
    const int r = ei[i];
    const int c = ei[N_EDGES + i];
    const float dx = pos[r * 3 + 0] - pos[c * 3 + 0];
    const float dy = pos[r * 3 + 1] - pos[c * 3 + 1];
    const float dz = pos[r * 3 + 2] - pos[c * 3 + 2];
    const float d  = __fsqrt_rn(dx * dx + dy * dy + dz * dz);
    const float C  = 0.5f * (__cosf(d * 0.31415926535f) + 1.f);
    const int p = atomicAdd(&hist[c], 1);
    float4 m;
    m.x = d; m.y = C;
    m.z = __int_as_float(r); m.w = __int_as_float(c);
    meta[p] = m;
}

// ---------------------------------------------------------------------------
// Fused edge kernel — byte-identical to R16-R19 (measured 268-270us).
// ---------------------------------------------------------------------------
__global__ __launch_bounds__(256, 2)
void edge_kernel(const float4* __restrict__ meta,
                 const float* __restrict__ w1, const float* __restrict__ b1,
                 const float* __restrict__ w2, const float* __restrict__ b2,
                 const unsigned short* __restrict__ xb, float* __restrict__ agg)
{
    extern __shared__ char lds[];
    char* w2t = lds;
    char* rb  = lds + 65536;          // tb = rb[0:16K]; ms = rb[0:8K]
    char* gsp = rb + 12288;           // gs = rb[12K:16K] (disjoint from ms+colsm)
    int* colsm = (int*)(rb + 8192);

    const int tid   = threadIdx.x;
    const int wave  = tid >> 6;
    const int l     = tid & 63;
    const int lrow  = l & 15;
    const int g     = l >> 4;
    const int kg    = g << 3;
    const int half  = blockIdx.x & 1;
    const int jblk  = half << 7;
    const int group = blockIdx.x >> 1;

    // stage W2^T half
    {
        const int j   = tid & 127;
        const int k2b = (tid >> 7) << 6;
        for (int i = 0; i < 64; ++i) {
            const int k = (k2b + i) * 2;
            const float v0 = w2[k * 256 + jblk + j];
            const float v1 = w2[(k + 1) * 256 + jblk + j];
            const unsigned pack = (unsigned)bfbits(v0) | ((unsigned)bfbits(v1) << 16);
            *(unsigned*)(w2t + ((j * 512 + k * 2) ^ ((j & 7) << 4))) = pack;
        }
    }

    // W1 B-fragments in registers (wave owns 64 filter cols)
    const float dlt    = 10.f / 49.f;
    const float coeff2 = (-0.5f / (dlt * dlt)) * 1.44269504f;   // log2e folded
    bf16x8 w1f[4][2];
    #pragma unroll
    for (int n = 0; n < 4; ++n)
        #pragma unroll
        for (int ks = 0; ks < 2; ++ks) {
            bf16x8 v;
            #pragma unroll
            for (int b = 0; b < 8; ++b) {
                const int k = (ks << 5) + kg + b;
                const int j = (wave << 6) + (n << 4) + lrow;
                v[b] = (k < 50) ? (__bf16)w1[k * 256 + j] : (__bf16)0.f;
            }
            w1f[n][ks] = v;
        }
    float b1v[4], b2v[2];
    #pragma unroll
    for (int n = 0; n < 4; ++n) b1v[n] = b1[(wave << 6) + (n << 4) + lrow];
    #pragma unroll
    for (int n = 0; n < 2; ++n) b2v[n] = b2[jblk + (wave << 5) + (n << 4) + lrow];

    BAR();   // w2t ready

    const f32x4 z4 = {0.f, 0.f, 0.f, 0.f};
    const int CH = (NTILES + 255) / 256;    // 49 tiles per group, contiguous
    const int t0 = group * CH;
    int t1 = t0 + CH; if (t1 > NTILES) t1 = NTILES;

    const int ge  = tid >> 3;         // gaussian producer: edge 0..31
    const int gkb = (tid & 7) << 3;   // gaussian producer: k-base

    // reader run-carry state (used by tid < 128 only)
    int   rprev  = -1;
    float rs     = 0.f;
    int   rfirst = 1;
    float* aj    = agg + jblk + (tid & 127);

    // meta prefetch
    float4 mv = meta[(t0 << 5) + (l & 31)];

    for (int t = t0; t < t1; ++t) {
        const float d  = mv.x;
        const float Cc = mv.y;
        const int   r  = __float_as_int(mv.z);
        const int   c  = __float_as_int(mv.w);
        if (t + 1 < t1) mv = meta[((t + 1) << 5) + (l & 31)];

        // hoisted bf16 x-gather (in flight until msg epilogue)
        float xv[2][2][4];
        #pragma unroll
        for (int m = 0; m < 2; ++m)
            #pragma unroll
            for (int r4 = 0; r4 < 4; ++r4) {
                const int e  = (m << 4) + (g << 2) + r4;
                const int re = __shfl(r, e, 64);
                #pragma unroll
                for (int n = 0; n < 2; ++n) {
                    const int jloc = (wave << 5) + (n << 4) + lrow;
                    xv[m][n][r4] = bf2f(xb[re * 256 + jblk + jloc]);
                }
            }

        // gaussian producer: thread (ge, gkb) computes 8 k-values for edge ge
        const float gd = __shfl(d, ge, 64);
        bf16x8 gv;
        #pragma unroll
        for (int b = 0; b < 8; ++b) {
            const int k = gkb + b;
            float gval = 0.f;
            if (k < 50) {
                const float u = gd - (float)k * dlt;
                gval = __builtin_amdgcn_exp2f(coeff2 * u * u);
            }
            gv[b] = (__bf16)gval;
        }
        // gs disjoint from reader's ms+colsm -> no pre-write barrier needed
        *(bf16x8*)(gsp + ((ge * 128 + (gkb << 1)) ^ ((ge & 7) << 4))) = gv;
        BAR();   // B2: gaussians visible

        // ---- GEMM1: gauss[32][64] @ W1 -> acc1 (wave owns 64 filter cols)
        bf16x8 af[2][2];
        #pragma unroll
        for (int m = 0; m < 2; ++m) {
            const int e = (m << 4) + lrow;
            #pragma unroll
            for (int ks = 0; ks < 2; ++ks)
                af[m][ks] = *(const bf16x8*)(gsp + ((e * 128 + ((ks << 5) + kg) * 2) ^ ((e & 7) << 4)));
        }
        f32x4 acc1[2][4];
        #pragma unroll
        for (int m = 0; m < 2; ++m)
            #pragma unroll
            for (int n = 0; n < 4; ++n) acc1[m][n] = z4;
        #pragma unroll
        for (int ks = 0; ks < 2; ++ks)
            #pragma unroll
            for (int m = 0; m < 2; ++m)
                #pragma unroll
                for (int n = 0; n < 4; ++n)
                    acc1[m][n] = __builtin_amdgcn_mfma_f32_16x16x32_bf16(af[m][ks], w1f[n][ks], acc1[m][n], 0, 0, 0);
        BAR();   // B3: gs reads done; tb region writable

        // ---- epilogue1: t = ssp(acc1 + b1) -> tb bf16 (swizzled)
        #pragma unroll
        for (int m = 0; m < 2; ++m)
            #pragma unroll
            for (int n = 0; n < 4; ++n)
                #pragma unroll
                for (int r4 = 0; r4 < 4; ++r4) {
                    const int e = (m << 4) + (g << 2) + r4;
                    const int k = (wave << 6) + (n << 4) + lrow;
                    const float v = ssp_f(acc1[m][n][r4] + b1v[n]);
                    *(__bf16*)(rb + ((e * 512 + k * 2) ^ ((e & 7) << 4))) = (__bf16)v;
                }
        BAR();   // B4: tb ready

        // ---- GEMM2: t[32][256] @ W2[:, jblk:+128] -> acc2
        f32x4 acc2[2][2];
        #pragma unroll
        for (int m = 0; m < 2; ++m) { acc2[m][0] = z4; acc2[m][1] = z4; }
        #pragma unroll
        for (int ks = 0; ks < 8; ++ks) {
            const int k0 = (ks << 5) + kg;
            bf16x8 bfr[2];
            #pragma unroll
            for (int n = 0; n < 2; ++n) {
                const int jl = (wave << 5) + (n << 4) + lrow;
                bfr[n] = *(const bf16x8*)(w2t + ((jl * 512 + k0 * 2) ^ ((jl & 7) << 4)));
            }
            #pragma unroll
            for (int m = 0; m < 2; ++m) {
                const int e = (m << 4) + lrow;
                const bf16x8 a = *(const bf16x8*)(rb + ((e * 512 + k0 * 2) ^ ((e & 7) << 4)));
                #pragma unroll
                for (int n = 0; n < 2; ++n)
                    acc2[m][n] = __builtin_amdgcn_mfma_f32_16x16x32_bf16(a, bfr[n], acc2[m][n], 0, 0, 0);
            }
        }
        BAR();   // B5: tb reads done; ms region writable

        // ---- msg epilogue: (acc2+b2)*C * xv -> ms[j][e] bf16 (swizzled)
        #pragma unroll
        for (int m = 0; m < 2; ++m) {
            const int base_e = (m << 4) + (g << 2);
            #pragma unroll
            for (int n = 0; n < 2; ++n) {
                const int jloc = (wave << 5) + (n << 4) + lrow;
                float vv[4];
                #pragma unroll
                for (int r4 = 0; r4 < 4; ++r4) {
                    const int e  = base_e + r4;
                    const float Ce = __shfl(Cc, e, 64);
                    vv[r4] = (acc2[m][n][r4] + b2v[n]) * Ce * xv[m][n][r4];
                }
                uint32x2 pk;
                pk[0] = (unsigned)bfbits(vv[0]) | ((unsigned)bfbits(vv[1]) << 16);
                pk[1] = (unsigned)bfbits(vv[2]) | ((unsigned)bfbits(vv[3]) << 16);
                *(uint32x2*)(rb + ((jloc * 64 + (base_e << 1)) ^ ((jloc & 7) << 4))) = pk;
            }
        }
        if (tid < 32) colsm[tid] = c;
        BAR();   // B6: ms + colsm ready

        // ---- reader: 128 threads, one j each, 32 edges; run-carry reduce
        if (tid < 128) {
            const int j = tid;
            const bf16x8 q0 = *(const bf16x8*)(rb + ((j * 64 +  0) ^ ((j & 7) << 4)));
            const bf16x8 q1 = *(const bf16x8*)(rb + ((j * 64 + 16) ^ ((j & 7) << 4)));
            const bf16x8 q2 = *(const bf16x8*)(rb + ((j * 64 + 32) ^ ((j & 7) << 4)));
            const bf16x8 q3 = *(const bf16x8*)(rb + ((j * 64 + 48) ^ ((j & 7) << 4)));
            #pragma unroll
            for (int e = 0; e < 32; ++e) {
                const float v = (float)(e < 8 ? q0[e] : e < 16 ? q1[e - 8] :
                                        e < 24 ? q2[e - 16] : q3[e - 24]);
                const int ce = colsm[e];
                if (ce != rprev) {                    // wave-uniform branch
                    if (rprev >= 0) {
                        if (rfirst) { atomicAdd(aj + rprev * 256, rs); rfirst = 0; }
                        else        { aj[rprev * 256] = rs; }
                    }
                    rs = 0.f; rprev = ce;
                }
                rs += v;
            }
        }
    }
    // final flush: run may continue into the next chunk -> atomic
    if (tid < 128 && rprev >= 0) atomicAdd(aj + rprev * 256, rs);
}

extern "C" void kernel_launch(void* const* d_in, const int* in_sizes, int n_in,
                              void* d_out, int out_size, void* d_ws, size_t ws_size,
                              hipStream_t stream)
{
    const float* h      = (const float*)d_in[0];
    const float* pos    = (const float*)d_in[1];
    const float* lin1_w = (const float*)d_in[2];
    const float* lin2_w = (const float*)d_in[3];
    const float* lin2_b = (const float*)d_in[4];
    const float* mlp_w1 = (const float*)d_in[5];
    const float* mlp_b1 = (const float*)d_in[6];
    const float* mlp_w2 = (const float*)d_in[7];
    const float* mlp_b2 = (const float*)d_in[8];
    const float* lin_w  = (const float*)d_in[9];
    const float* lin_b  = (const float*)d_in[10];
    const int*   ei     = (const int*)d_in[11];
    float* out = (float*)d_out;

    // ws layout: xb bf16 12.8M | agg 25.6M | meta 6.4M | hist 0.1M | Bt x3
    unsigned short* xb  = (unsigned short*)d_ws;
    float*  agg  = (float*)((char*)d_ws + 12800000);
    float4* meta = (float4*)((char*)d_ws + 38400000);
    int*    hist = (int*)((char*)d_ws + 44800000);
    __bf16* bt0  = (__bf16*)((char*)d_ws + 44900000);   // 131072 B each
    __bf16* bt1  = bt0 + 65536;
    __bf16* bt2  = bt1 + 65536;

    (void)hipFuncSetAttribute((const void*)edge_kernel,
                              hipFuncAttributeMaxDynamicSharedMemorySize, 81920);

    const dim3 blk(256);

    // B^T bf16 conversion + hist zero
    convt_kernel<<<dim3(768), blk, 0, stream>>>(lin1_w, lin2_w, lin_w, bt0, bt1, bt2, hist);

    // x = bf16(h @ lin1_w)  MERGED WITH  hist atomics + agg zero
    gemm0_hist<<<dim3(MT + EB), blk, 0, stream>>>(h, bt0, xb, N_NODES, ei, hist, (float4*)agg);

    scan_kernel<<<dim3(1), dim3(1024), 0, stream>>>(hist);
    scatter_meta<<<dim3(EB), blk, 0, stream>>>(ei, pos, hist, meta, out + N_NODES * 256);

    // fused edge pipeline -> agg
    edge_kernel<<<dim3(512), blk, 81920, stream>>>(meta, mlp_w1, mlp_b1,
                                                   mlp_w2, mlp_b2, xb, agg);

    // out = ssp(agg @ lin2_w + lin2_b) @ lin_w + lin_b  (fused, one kernel)
    fused_tail<<<dim3(MT), blk, 0, stream>>>(agg, bt1, lin2_b, bt2, lin_b, out, N_NODES);
}